// Round 2
// baseline (1666.375 us; speedup 1.0000x reference)
//
#include <hip/hip_runtime.h>

// ---------------------------------------------------------------------------
// Encoder_Decoder: 80-class bidirectional GRU encoder (H=128) + GRU decoder
// (DH=256) with teacher forcing, plus two shared dense layers.
// Strategy: GRU recurrences with per-row weights in registers as packed f16,
// v_dot2_f32_f16 matvecs, h broadcast via LDS; decoder input projections
// precomputed (only 3 distinct inputs due to teacher forcing); log_softmax
// fused into the decoder loop.
// ---------------------------------------------------------------------------

typedef __fp16 h2v __attribute__((ext_vector_type(2)));

#define HAVE_FDOT2 1

__device__ __forceinline__ h2v pk2(float a, float b) {
  return __builtin_amdgcn_cvt_pkrtz(a, b);
}
__device__ __forceinline__ unsigned h2u(h2v h) { return __builtin_bit_cast(unsigned, h); }
__device__ __forceinline__ h2v u2h(unsigned u) { return __builtin_bit_cast(h2v, u); }
__device__ __forceinline__ float fdot2f(h2v a, h2v b, float c) {
#if HAVE_FDOT2 && __has_builtin(__builtin_amdgcn_fdot2)
  return __builtin_amdgcn_fdot2(a, b, c, false);
#else
  return c + (float)a.x * (float)b.x + (float)a.y * (float)b.y;
#endif
}
__device__ __forceinline__ float sigf(float x) { return 1.f / (1.f + __expf(-x)); }
__device__ __forceinline__ float tanhfast(float x) { return 2.f / (1.f + __expf(-2.f * x)) - 1.f; }

// ---------------------------------------------------------------------------
// K0: fill allf[:,128:224] with score|box|origin_score
// ---------------------------------------------------------------------------
__global__ void k_fill_misc(const float* __restrict__ score, const float* __restrict__ box,
                            const float* __restrict__ orig, float* __restrict__ allf) {
  int i = blockIdx.x * blockDim.x + threadIdx.x;
  if (i >= 40960 * 96) return;
  int row = i / 96, k = i - row * 96;
  float v;
  if (k == 0) v = score[row];
  else if (k < 5) v = box[row * 4 + (k - 1)];
  else v = orig[(size_t)row * 91 + (k - 5)];
  allf[(size_t)row * 224 + 128 + k] = v;
}

// ---------------------------------------------------------------------------
// K1: allf[:,0:128] = relu(feat @ appear_W^T + appear_b)   (40960x1024 @ 1024x128)
// fp32 LDS-tiled GEMM. BM=64, BN=128(all), BK=32, 256 threads, 4x8 microtile.
// ---------------------------------------------------------------------------
__global__ __launch_bounds__(256) void k_gemm_appear(
    const float* __restrict__ A, const float* __restrict__ W,
    const float* __restrict__ bias, float* __restrict__ allf) {
  __shared__ float As[32][68];   // [k][row], rows 16B-aligned (68*4=272=17*16)
  __shared__ float Ws[32][132];  // [k][col]
  const int tid = threadIdx.x;
  const int tx = tid & 15, ty = tid >> 4;
  const int r0 = blockIdx.x * 64;
  const int lr = tid >> 3;          // 0..31
  const int lk = (tid & 7) * 4;     // 0,4,..,28
  float acc[4][8];
#pragma unroll
  for (int i = 0; i < 4; ++i)
#pragma unroll
    for (int j = 0; j < 8; ++j) acc[i][j] = 0.f;

  for (int k0 = 0; k0 < 1024; k0 += 32) {
#pragma unroll
    for (int i = 0; i < 2; ++i) {
      int rr = lr + i * 32;
      float4 v = *(const float4*)(A + (size_t)(r0 + rr) * 1024 + k0 + lk);
      As[lk + 0][rr] = v.x; As[lk + 1][rr] = v.y; As[lk + 2][rr] = v.z; As[lk + 3][rr] = v.w;
    }
#pragma unroll
    for (int i = 0; i < 4; ++i) {
      int wr = lr + i * 32;
      float4 v = *(const float4*)(W + (size_t)wr * 1024 + k0 + lk);
      Ws[lk + 0][wr] = v.x; Ws[lk + 1][wr] = v.y; Ws[lk + 2][wr] = v.z; Ws[lk + 3][wr] = v.w;
    }
    __syncthreads();
#pragma unroll
    for (int kk = 0; kk < 32; ++kk) {
      float4 a = *(const float4*)&As[kk][ty * 4];
      float4 w0 = *(const float4*)&Ws[kk][tx * 8];
      float4 w1 = *(const float4*)&Ws[kk][tx * 8 + 4];
      float av[4] = {a.x, a.y, a.z, a.w};
      float wv[8] = {w0.x, w0.y, w0.z, w0.w, w1.x, w1.y, w1.z, w1.w};
#pragma unroll
      for (int i = 0; i < 4; ++i)
#pragma unroll
        for (int j = 0; j < 8; ++j) acc[i][j] = fmaf(av[i], wv[j], acc[i][j]);
    }
    __syncthreads();
  }
#pragma unroll
  for (int i = 0; i < 4; ++i) {
    int row = r0 + ty * 4 + i;
#pragma unroll
    for (int j = 0; j < 8; ++j) {
      int col = tx * 8 + j;
      float v = acc[i][j] + bias[col];
      allf[(size_t)row * 224 + col] = fmaxf(v, 0.f);
    }
  }
}

// ---------------------------------------------------------------------------
// K2: enc_feat = relu(allf @ featlin_W^T + b), stored as packed f16x2 (row*64 u32)
// ---------------------------------------------------------------------------
__global__ __launch_bounds__(256) void k_gemm_featlin(
    const float* __restrict__ A, const float* __restrict__ W,
    const float* __restrict__ bias, unsigned* __restrict__ encf2) {
  __shared__ float As[32][68];
  __shared__ float Ws[32][132];
  const int tid = threadIdx.x;
  const int tx = tid & 15, ty = tid >> 4;
  const int r0 = blockIdx.x * 64;
  const int lr = tid >> 3;
  const int lk = (tid & 7) * 4;
  float acc[4][8];
#pragma unroll
  for (int i = 0; i < 4; ++i)
#pragma unroll
    for (int j = 0; j < 8; ++j) acc[i][j] = 0.f;

  for (int k0 = 0; k0 < 224; k0 += 32) {
#pragma unroll
    for (int i = 0; i < 2; ++i) {
      int rr = lr + i * 32;
      float4 v = *(const float4*)(A + (size_t)(r0 + rr) * 224 + k0 + lk);
      As[lk + 0][rr] = v.x; As[lk + 1][rr] = v.y; As[lk + 2][rr] = v.z; As[lk + 3][rr] = v.w;
    }
#pragma unroll
    for (int i = 0; i < 4; ++i) {
      int wr = lr + i * 32;
      float4 v = *(const float4*)(W + (size_t)wr * 224 + k0 + lk);
      Ws[lk + 0][wr] = v.x; Ws[lk + 1][wr] = v.y; Ws[lk + 2][wr] = v.z; Ws[lk + 3][wr] = v.w;
    }
    __syncthreads();
#pragma unroll
    for (int kk = 0; kk < 32; ++kk) {
      float4 a = *(const float4*)&As[kk][ty * 4];
      float4 w0 = *(const float4*)&Ws[kk][tx * 8];
      float4 w1 = *(const float4*)&Ws[kk][tx * 8 + 4];
      float av[4] = {a.x, a.y, a.z, a.w};
      float wv[8] = {w0.x, w0.y, w0.z, w0.w, w1.x, w1.y, w1.z, w1.w};
#pragma unroll
      for (int i = 0; i < 4; ++i)
#pragma unroll
        for (int j = 0; j < 8; ++j) acc[i][j] = fmaf(av[i], wv[j], acc[i][j]);
    }
    __syncthreads();
  }
#pragma unroll
  for (int i = 0; i < 4; ++i) {
    int row = r0 + ty * 4 + i;
    unsigned* orow = encf2 + (size_t)row * 64;
#pragma unroll
    for (int p = 0; p < 4; ++p) {
      int col = tx * 8 + 2 * p;
      float a = fmaxf(acc[i][2 * p] + bias[col], 0.f);
      float b = fmaxf(acc[i][2 * p + 1] + bias[col + 1], 0.f);
      orow[tx * 4 + p] = h2u(pk2(a, b));
    }
  }
}

// ---------------------------------------------------------------------------
// K3: decoder input projections: gi[c][v][r] = dec_Wih[c][r]@dec_emb[v] + dec_bih[c][r]
// ---------------------------------------------------------------------------
__global__ __launch_bounds__(256) void k_dec_gi(
    const float* __restrict__ Wih, const float* __restrict__ bih,
    const float* __restrict__ emb, float* __restrict__ gi) {
  __shared__ float e[4][32];
  const int c = blockIdx.x, tid = threadIdx.x;
  if (tid < 128) e[tid >> 5][tid & 31] = emb[tid];
  __syncthreads();
#pragma unroll
  for (int i = 0; i < 3; ++i) {
    int r = tid + i * 256;
    const float* w = Wih + ((size_t)c * 768 + r) * 32;
    float b = bih[(size_t)c * 768 + r];
    float a0 = b, a1 = b, a2 = b, a3 = b;
#pragma unroll
    for (int k = 0; k < 32; ++k) {
      float wv = w[k];
      a0 = fmaf(wv, e[0][k], a0);
      a1 = fmaf(wv, e[1][k], a1);
      a2 = fmaf(wv, e[2][k], a2);
      a3 = fmaf(wv, e[3][k], a3);
    }
    gi[((size_t)c * 4 + 0) * 768 + r] = a0;
    gi[((size_t)c * 4 + 1) * 768 + r] = a1;
    gi[((size_t)c * 4 + 2) * 768 + r] = a2;
    gi[((size_t)c * 4 + 3) * 768 + r] = a3;
  }
}

// ---------------------------------------------------------------------------
// K4: per-(class,dir) encoder GRU, 513 steps. 160 blocks x 512 threads.
// Threads 0..383: one gate-row each, Wih+Whh rows in registers (f16x2).
// Threads 448..511: prefetch next x row. Threads 0..127 combine gates.
// Only final hidden is kept -> dec_h0.
// ---------------------------------------------------------------------------
__global__ __launch_bounds__(512) void k_enc_gru(
    const unsigned* __restrict__ encf2,
    const float* __restrict__ WihF, const float* __restrict__ WhhF,
    const float* __restrict__ bihF, const float* __restrict__ bhhF,
    const float* __restrict__ WihB, const float* __restrict__ WhhB,
    const float* __restrict__ bihB, const float* __restrict__ bhhB,
    float* __restrict__ dec_h0) {
  const int blk = blockIdx.x;
  const int c = blk >> 1, dir = blk & 1;
  const int tid = threadIdx.x;

  const float* Wih = (dir ? WihB : WihF) + (size_t)c * 384 * 128;
  const float* Whh = (dir ? WhhB : WhhF) + (size_t)c * 384 * 128;
  const float* bih = (dir ? bihB : bihF) + (size_t)c * 384;
  const float* bhh = (dir ? bhhB : bhhF) + (size_t)c * 384;

  __shared__ __align__(16) unsigned x2s[2][64];
  __shared__ __align__(16) unsigned h2s[64];
  __shared__ float iis[384];
  __shared__ float hhs[384];

  h2v wih[64], whh[64];
  float bi = 0.f, bh = 0.f;
  if (tid < 384) {
    const float4* w4 = (const float4*)(Wih + (size_t)tid * 128);
#pragma unroll
    for (int k = 0; k < 32; ++k) {
      float4 v = w4[k];
      wih[2 * k] = pk2(v.x, v.y);
      wih[2 * k + 1] = pk2(v.z, v.w);
    }
    const float4* u4 = (const float4*)(Whh + (size_t)tid * 128);
#pragma unroll
    for (int k = 0; k < 32; ++k) {
      float4 v = u4[k];
      whh[2 * k] = pk2(v.x, v.y);
      whh[2 * k + 1] = pk2(v.z, v.w);
    }
    bi = bih[tid];
    bh = bhh[tid];
  }
  if (tid < 64) h2s[tid] = 0u;
  if (tid >= 448) {  // x for t=0: fwd row 0, bwd EOS(ones)
    int lane = tid - 448;
    x2s[0][lane] = (dir == 0) ? encf2[((size_t)c * 512 + 0) * 64 + lane] : 0x3C003C00u;
  }
  float hreg = 0.f;
  __syncthreads();

  for (int t = 0; t <= 512; ++t) {
    if (tid < 384) {
      float aI = bi, aH = bh;
      const uint4* xp = (const uint4*)(&x2s[t & 1][0]);
      const uint4* hp = (const uint4*)(&h2s[0]);
#pragma unroll
      for (int k = 0; k < 16; ++k) {
        uint4 x = xp[k];
        aI = fdot2f(wih[4 * k + 0], u2h(x.x), aI);
        aI = fdot2f(wih[4 * k + 1], u2h(x.y), aI);
        aI = fdot2f(wih[4 * k + 2], u2h(x.z), aI);
        aI = fdot2f(wih[4 * k + 3], u2h(x.w), aI);
      }
#pragma unroll
      for (int k = 0; k < 16; ++k) {
        uint4 h = hp[k];
        aH = fdot2f(whh[4 * k + 0], u2h(h.x), aH);
        aH = fdot2f(whh[4 * k + 1], u2h(h.y), aH);
        aH = fdot2f(whh[4 * k + 2], u2h(h.z), aH);
        aH = fdot2f(whh[4 * k + 3], u2h(h.w), aH);
      }
      iis[tid] = aI;
      hhs[tid] = aH;
    } else if (tid >= 448) {
      if (t < 512) {  // prefetch x for t+1 into other buffer
        int tn = t + 1, lane = tid - 448;
        int row;
        if (dir == 0) row = (tn < 512) ? tn : -1;   // t=512 is EOS
        else row = 512 - tn;                         // tn in 1..512 -> rows 511..0
        x2s[tn & 1][lane] = (row < 0) ? 0x3C003C00u
                                      : encf2[((size_t)c * 512 + row) * 64 + lane];
      }
    }
    __syncthreads();
    if (tid < 128) {
      float rg = sigf(iis[tid] + hhs[tid]);
      float z = sigf(iis[128 + tid] + hhs[128 + tid]);
      float nn = tanhfast(iis[256 + tid] + rg * hhs[256 + tid]);
      float hn = (1.f - z) * nn + z * hreg;
      hreg = hn;
      float other = __shfl_xor(hn, 1, 64);
      if ((tid & 1) == 0) h2s[tid >> 1] = h2u(pk2(hn, other));
    }
    __syncthreads();
  }
  if (tid < 128) dec_h0[(size_t)c * 256 + dir * 128 + tid] = hreg;
}

// ---------------------------------------------------------------------------
// K5: per-class decoder GRU + fused out-projection + log_softmax.
// 80 blocks x 768 threads; each thread owns one Whh row (256 f16 = 128 VGPR).
// ---------------------------------------------------------------------------
__global__ __launch_bounds__(768) void k_dec_gru(
    const float* __restrict__ Whh, const float* __restrict__ bhh,
    const float* __restrict__ gi, const float* __restrict__ h0,
    const int* __restrict__ labels,
    const float* __restrict__ outW, const float* __restrict__ outB,
    float* __restrict__ out) {
  const int c = blockIdx.x, tid = threadIdx.x;
  __shared__ __align__(16) unsigned h2s[128];
  __shared__ float gsum[512];
  __shared__ float gni[256], gnh[256];
  __shared__ int labs[512];
  __shared__ float red[4][4];

  h2v whh[128];
  {
    const float4* w4 = (const float4*)(Whh + ((size_t)c * 768 + tid) * 256);
#pragma unroll
    for (int k = 0; k < 64; ++k) {
      float4 v = w4[k];
      whh[2 * k] = pk2(v.x, v.y);
      whh[2 * k + 1] = pk2(v.z, v.w);
    }
  }
  float bh = bhh[(size_t)c * 768 + tid];
  float g0 = gi[((size_t)c * 4 + 0) * 768 + tid];
  float g1 = gi[((size_t)c * 4 + 1) * 768 + tid];
  float g2 = gi[((size_t)c * 4 + 2) * 768 + tid];  // SOS
  if (tid < 512) labs[tid] = labels[(size_t)c * 512 + tid];
  float b0 = outB[0], b1 = outB[1], b2 = outB[2], b3 = outB[3];
  float hreg = 0.f, ow0 = 0.f, ow1 = 0.f, ow2 = 0.f, ow3 = 0.f;
  if (tid < 256) {
    hreg = h0[(size_t)c * 256 + tid];
    ow0 = outW[tid];
    ow1 = outW[256 + tid];
    ow2 = outW[512 + tid];
    ow3 = outW[768 + tid];
    float other = __shfl_xor(hreg, 1, 64);
    if ((tid & 1) == 0) h2s[tid >> 1] = h2u(pk2(hreg, other));
  }
  __syncthreads();

  for (int t = 0; t <= 512; ++t) {
    {
      float aH = bh;
      const uint4* hp = (const uint4*)(&h2s[0]);
#pragma unroll
      for (int k = 0; k < 32; ++k) {
        uint4 h = hp[k];
        aH = fdot2f(whh[4 * k + 0], u2h(h.x), aH);
        aH = fdot2f(whh[4 * k + 1], u2h(h.y), aH);
        aH = fdot2f(whh[4 * k + 2], u2h(h.z), aH);
        aH = fdot2f(whh[4 * k + 3], u2h(h.w), aH);
      }
      float ii = (t == 0) ? g2 : (labs[t - 1] ? g1 : g0);
      if (tid < 512) gsum[tid] = ii + aH;
      else {
        gni[tid - 512] = ii;
        gnh[tid - 512] = aH;
      }
    }
    __syncthreads();
    if (tid < 256) {
      float rg = sigf(gsum[tid]);
      float z = sigf(gsum[256 + tid]);
      float nn = tanhfast(gni[tid] + rg * gnh[tid]);
      float hn = (1.f - z) * nn + z * hreg;
      hreg = hn;
      float other = __shfl_xor(hn, 1, 64);
      if ((tid & 1) == 0) h2s[tid >> 1] = h2u(pk2(hn, other));
      float p0 = ow0 * hn, p1 = ow1 * hn, p2 = ow2 * hn, p3 = ow3 * hn;
#pragma unroll
      for (int off = 32; off > 0; off >>= 1) {
        p0 += __shfl_xor(p0, off, 64);
        p1 += __shfl_xor(p1, off, 64);
        p2 += __shfl_xor(p2, off, 64);
        p3 += __shfl_xor(p3, off, 64);
      }
      if ((tid & 63) == 0) {
        int w = tid >> 6;
        red[w][0] = p0; red[w][1] = p1; red[w][2] = p2; red[w][3] = p3;
      }
    }
    __syncthreads();
    if (tid == 0) {
      float l0 = red[0][0] + red[1][0] + red[2][0] + red[3][0] + b0;
      float l1 = red[0][1] + red[1][1] + red[2][1] + red[3][1] + b1;
      float l2 = red[0][2] + red[1][2] + red[2][2] + red[3][2] + b2;
      float l3 = red[0][3] + red[1][3] + red[2][3] + red[3][3] + b3;
      float m = fmaxf(fmaxf(l0, l1), fmaxf(l2, l3));
      float s = __expf(l0 - m) + __expf(l1 - m) + __expf(l2 - m) + __expf(l3 - m);
      float lse = m + __logf(s);
      float* o = out + ((size_t)c * 513 + t) * 4;
      o[0] = l0 - lse; o[1] = l1 - lse; o[2] = l2 - lse; o[3] = l3 - lse;
    }
  }
}

// ---------------------------------------------------------------------------
// K6: labels (as float) and weights passthrough
// ---------------------------------------------------------------------------
__global__ void k_passthrough(const int* __restrict__ labels,
                              const float* __restrict__ weights,
                              float* __restrict__ out) {
  int i = blockIdx.x * blockDim.x + threadIdx.x;
  if (i < 40960) {
    out[164160 + i] = (float)labels[i];
    out[164160 + 40960 + i] = weights[i];
  }
}

// ---------------------------------------------------------------------------
extern "C" void kernel_launch(void* const* d_in, const int* in_sizes, int n_in,
                              void* d_out, int out_size, void* d_ws, size_t ws_size,
                              hipStream_t stream) {
  (void)in_sizes; (void)n_in; (void)out_size; (void)ws_size;
  const float* feat = (const float*)d_in[0];
  const float* score = (const float*)d_in[1];
  const float* box = (const float*)d_in[2];
  const float* orig = (const float*)d_in[3];
  const int* labels = (const int*)d_in[4];
  const float* weights = (const float*)d_in[5];
  const float* appear_W = (const float*)d_in[8];
  const float* appear_b = (const float*)d_in[9];
  const float* featlin_W = (const float*)d_in[10];
  const float* featlin_b = (const float*)d_in[11];
  const float* eWihF = (const float*)d_in[12];
  const float* eWhhF = (const float*)d_in[13];
  const float* ebihF = (const float*)d_in[14];
  const float* ebhhF = (const float*)d_in[15];
  const float* eWihB = (const float*)d_in[16];
  const float* eWhhB = (const float*)d_in[17];
  const float* ebihB = (const float*)d_in[18];
  const float* ebhhB = (const float*)d_in[19];
  const float* dec_emb = (const float*)d_in[20];
  const float* dWih = (const float*)d_in[21];
  const float* dWhh = (const float*)d_in[22];
  const float* dbih = (const float*)d_in[23];
  const float* dbhh = (const float*)d_in[24];
  const float* outW = (const float*)d_in[25];
  const float* outB = (const float*)d_in[26];
  float* out = (float*)d_out;

  char* ws = (char*)d_ws;
  float* allf = (float*)ws;                                   // 40960*224 f32
  unsigned* encf2 = (unsigned*)(ws + (size_t)40960 * 224 * 4);  // 40960*64 u32
  float* dec_h0 = (float*)(ws + (size_t)40960 * 224 * 4 + (size_t)40960 * 64 * 4);
  float* dec_gi = dec_h0 + 80 * 256;                          // 80*4*768 f32

  k_fill_misc<<<15360, 256, 0, stream>>>(score, box, orig, allf);
  k_gemm_appear<<<640, 256, 0, stream>>>(feat, appear_W, appear_b, allf);
  k_gemm_featlin<<<640, 256, 0, stream>>>(allf, featlin_W, featlin_b, encf2);
  k_dec_gi<<<80, 256, 0, stream>>>(dWih, dbih, dec_emb, dec_gi);
  k_enc_gru<<<160, 512, 0, stream>>>(encf2, eWihF, eWhhF, ebihF, ebhhF,
                                     eWihB, eWhhB, ebihB, ebhhB, dec_h0);
  k_dec_gru<<<80, 768, 0, stream>>>(dWhh, dbhh, dec_gi, dec_h0, labels, outW, outB, out);
  k_passthrough<<<160, 256, 0, stream>>>(labels, weights, out);
}

// Round 3
// 1652.281 us; speedup vs baseline: 1.0085x; 1.0085x over previous
//
#include <hip/hip_runtime.h>

// ---------------------------------------------------------------------------
// Encoder_Decoder: 80-class bidirectional GRU encoder (H=128) + GRU decoder
// (DH=256) with teacher forcing, plus two shared dense layers.
// v3: column-partitioned matvec, weights resident in VGPRs (f16x2), partial
// sums reduced across 16-lane groups via DPP/ds_swizzle xor-butterfly.
// Decoder: __launch_bounds__(768,3) -> 170 VGPR cap (prevents the v2 spill).
// ---------------------------------------------------------------------------

typedef __fp16 h2v __attribute__((ext_vector_type(2)));

__device__ __forceinline__ h2v pk2(float a, float b) {
  return __builtin_amdgcn_cvt_pkrtz(a, b);
}
__device__ __forceinline__ unsigned h2u(h2v h) { return __builtin_bit_cast(unsigned, h); }
__device__ __forceinline__ h2v u2h(unsigned u) { return __builtin_bit_cast(h2v, u); }
__device__ __forceinline__ float fdot2f(h2v a, h2v b, float c) {
  return __builtin_amdgcn_fdot2(a, b, c, false);
}
__device__ __forceinline__ float sigf(float x) { return 1.f / (1.f + __expf(-x)); }
__device__ __forceinline__ float tanhfast(float x) { return 2.f / (1.f + __expf(-2.f * x)) - 1.f; }

// acc + (partner-lane v) via DPP. CTRL: 0xB1 = quad_perm[1,0,3,2] (xor1),
// 0x4E = quad_perm[2,3,0,1] (xor2), 0x128 = row_ror:8 (xor8 within 16-row).
template <int CTRL>
__device__ __forceinline__ float dppadd(float acc, float v) {
  int r = __builtin_amdgcn_update_dpp(0, __float_as_int(v), CTRL, 0xF, 0xF, true);
  return acc + __int_as_float(r);
}
// xor-4 via ds_swizzle BitMode: (4<<10)|0x1F
__device__ __forceinline__ float swz4add(float acc, float v) {
  return acc + __int_as_float(__builtin_amdgcn_ds_swizzle(__float_as_int(v), 0x101F));
}

// Reduce 8 partials (slot k on lane holds row-id k^(m&7)) across a 16-lane
// group; returns the full sum for row-id (m&7) (identical on lanes m, m^8).
__device__ __forceinline__ float reduce8(float p[8]) {
  p[0] = dppadd<0xB1>(p[0], p[1]);
  p[2] = dppadd<0xB1>(p[2], p[3]);
  p[4] = dppadd<0xB1>(p[4], p[5]);
  p[6] = dppadd<0xB1>(p[6], p[7]);
  p[0] = dppadd<0x4E>(p[0], p[2]);
  p[4] = dppadd<0x4E>(p[4], p[6]);
  p[0] = swz4add(p[0], p[4]);
  p[0] = dppadd<0x128>(p[0], p[0]);
  return p[0];
}

// ---------------------------------------------------------------------------
// K0: fill allf[:,128:224] with score|box|origin_score
// ---------------------------------------------------------------------------
__global__ void k_fill_misc(const float* __restrict__ score, const float* __restrict__ box,
                            const float* __restrict__ orig, float* __restrict__ allf) {
  int i = blockIdx.x * blockDim.x + threadIdx.x;
  if (i >= 40960 * 96) return;
  int row = i / 96, k = i - row * 96;
  float v;
  if (k == 0) v = score[row];
  else if (k < 5) v = box[row * 4 + (k - 1)];
  else v = orig[(size_t)row * 91 + (k - 5)];
  allf[(size_t)row * 224 + 128 + k] = v;
}

// ---------------------------------------------------------------------------
// K1: allf[:,0:128] = relu(feat @ appear_W^T + appear_b)
// ---------------------------------------------------------------------------
__global__ __launch_bounds__(256) void k_gemm_appear(
    const float* __restrict__ A, const float* __restrict__ W,
    const float* __restrict__ bias, float* __restrict__ allf) {
  __shared__ float As[32][68];
  __shared__ float Ws[32][132];
  const int tid = threadIdx.x;
  const int tx = tid & 15, ty = tid >> 4;
  const int r0 = blockIdx.x * 64;
  const int lr = tid >> 3;
  const int lk = (tid & 7) * 4;
  float acc[4][8];
#pragma unroll
  for (int i = 0; i < 4; ++i)
#pragma unroll
    for (int j = 0; j < 8; ++j) acc[i][j] = 0.f;

  for (int k0 = 0; k0 < 1024; k0 += 32) {
#pragma unroll
    for (int i = 0; i < 2; ++i) {
      int rr = lr + i * 32;
      float4 v = *(const float4*)(A + (size_t)(r0 + rr) * 1024 + k0 + lk);
      As[lk + 0][rr] = v.x; As[lk + 1][rr] = v.y; As[lk + 2][rr] = v.z; As[lk + 3][rr] = v.w;
    }
#pragma unroll
    for (int i = 0; i < 4; ++i) {
      int wr = lr + i * 32;
      float4 v = *(const float4*)(W + (size_t)wr * 1024 + k0 + lk);
      Ws[lk + 0][wr] = v.x; Ws[lk + 1][wr] = v.y; Ws[lk + 2][wr] = v.z; Ws[lk + 3][wr] = v.w;
    }
    __syncthreads();
#pragma unroll
    for (int kk = 0; kk < 32; ++kk) {
      float4 a = *(const float4*)&As[kk][ty * 4];
      float4 w0 = *(const float4*)&Ws[kk][tx * 8];
      float4 w1 = *(const float4*)&Ws[kk][tx * 8 + 4];
      float av[4] = {a.x, a.y, a.z, a.w};
      float wv[8] = {w0.x, w0.y, w0.z, w0.w, w1.x, w1.y, w1.z, w1.w};
#pragma unroll
      for (int i = 0; i < 4; ++i)
#pragma unroll
        for (int j = 0; j < 8; ++j) acc[i][j] = fmaf(av[i], wv[j], acc[i][j]);
    }
    __syncthreads();
  }
#pragma unroll
  for (int i = 0; i < 4; ++i) {
    int row = r0 + ty * 4 + i;
#pragma unroll
    for (int j = 0; j < 8; ++j) {
      int col = tx * 8 + j;
      float v = acc[i][j] + bias[col];
      allf[(size_t)row * 224 + col] = fmaxf(v, 0.f);
    }
  }
}

// ---------------------------------------------------------------------------
// K2: enc_feat = relu(allf @ featlin_W^T + b), stored packed f16x2
// ---------------------------------------------------------------------------
__global__ __launch_bounds__(256) void k_gemm_featlin(
    const float* __restrict__ A, const float* __restrict__ W,
    const float* __restrict__ bias, unsigned* __restrict__ encf2) {
  __shared__ float As[32][68];
  __shared__ float Ws[32][132];
  const int tid = threadIdx.x;
  const int tx = tid & 15, ty = tid >> 4;
  const int r0 = blockIdx.x * 64;
  const int lr = tid >> 3;
  const int lk = (tid & 7) * 4;
  float acc[4][8];
#pragma unroll
  for (int i = 0; i < 4; ++i)
#pragma unroll
    for (int j = 0; j < 8; ++j) acc[i][j] = 0.f;

  for (int k0 = 0; k0 < 224; k0 += 32) {
#pragma unroll
    for (int i = 0; i < 2; ++i) {
      int rr = lr + i * 32;
      float4 v = *(const float4*)(A + (size_t)(r0 + rr) * 224 + k0 + lk);
      As[lk + 0][rr] = v.x; As[lk + 1][rr] = v.y; As[lk + 2][rr] = v.z; As[lk + 3][rr] = v.w;
    }
#pragma unroll
    for (int i = 0; i < 4; ++i) {
      int wr = lr + i * 32;
      float4 v = *(const float4*)(W + (size_t)wr * 224 + k0 + lk);
      Ws[lk + 0][wr] = v.x; Ws[lk + 1][wr] = v.y; Ws[lk + 2][wr] = v.z; Ws[lk + 3][wr] = v.w;
    }
    __syncthreads();
#pragma unroll
    for (int kk = 0; kk < 32; ++kk) {
      float4 a = *(const float4*)&As[kk][ty * 4];
      float4 w0 = *(const float4*)&Ws[kk][tx * 8];
      float4 w1 = *(const float4*)&Ws[kk][tx * 8 + 4];
      float av[4] = {a.x, a.y, a.z, a.w};
      float wv[8] = {w0.x, w0.y, w0.z, w0.w, w1.x, w1.y, w1.z, w1.w};
#pragma unroll
      for (int i = 0; i < 4; ++i)
#pragma unroll
        for (int j = 0; j < 8; ++j) acc[i][j] = fmaf(av[i], wv[j], acc[i][j]);
    }
    __syncthreads();
  }
#pragma unroll
  for (int i = 0; i < 4; ++i) {
    int row = r0 + ty * 4 + i;
    unsigned* orow = encf2 + (size_t)row * 64;
#pragma unroll
    for (int p = 0; p < 4; ++p) {
      int col = tx * 8 + 2 * p;
      float a = fmaxf(acc[i][2 * p] + bias[col], 0.f);
      float b = fmaxf(acc[i][2 * p + 1] + bias[col + 1], 0.f);
      orow[tx * 4 + p] = h2u(pk2(a, b));
    }
  }
}

// ---------------------------------------------------------------------------
// K3: decoder input projections: gi[c][v][r] = dec_Wih[c][r]@dec_emb[v] + bih
// ---------------------------------------------------------------------------
__global__ __launch_bounds__(256) void k_dec_gi(
    const float* __restrict__ Wih, const float* __restrict__ bih,
    const float* __restrict__ emb, float* __restrict__ gi) {
  __shared__ float e[4][32];
  const int c = blockIdx.x, tid = threadIdx.x;
  if (tid < 128) e[tid >> 5][tid & 31] = emb[tid];
  __syncthreads();
#pragma unroll
  for (int i = 0; i < 3; ++i) {
    int r = tid + i * 256;
    const float* w = Wih + ((size_t)c * 768 + r) * 32;
    float b = bih[(size_t)c * 768 + r];
    float a0 = b, a1 = b, a2 = b, a3 = b;
#pragma unroll
    for (int k = 0; k < 32; ++k) {
      float wv = w[k];
      a0 = fmaf(wv, e[0][k], a0);
      a1 = fmaf(wv, e[1][k], a1);
      a2 = fmaf(wv, e[2][k], a2);
      a3 = fmaf(wv, e[3][k], a3);
    }
    gi[((size_t)c * 4 + 0) * 768 + r] = a0;
    gi[((size_t)c * 4 + 1) * 768 + r] = a1;
    gi[((size_t)c * 4 + 2) * 768 + r] = a2;
    gi[((size_t)c * 4 + 3) * 768 + r] = a3;
  }
}

// ---------------------------------------------------------------------------
// K4: per-(class,dir) encoder GRU, 513 steps. 160 blocks x 512 threads.
// 8 waves; each wave: 32 combined r/z rows (Wih·x + Whh·h fused) + 32 single
// rows (i_n for w<4, h_n for w>=4). 16-lane group owns 16 rows x 8 cols.
// ---------------------------------------------------------------------------
__global__ __launch_bounds__(512, 2) void k_enc_gru(
    const unsigned* __restrict__ encf2,
    const float* __restrict__ WihF, const float* __restrict__ WhhF,
    const float* __restrict__ bihF, const float* __restrict__ bhhF,
    const float* __restrict__ WihB, const float* __restrict__ WhhB,
    const float* __restrict__ bihB, const float* __restrict__ bhhB,
    float* __restrict__ dec_h0) {
  const int blk = blockIdx.x;
  const int c = blk >> 1, dir = blk & 1;
  const int tid = threadIdx.x;
  const int w = tid >> 6, l = tid & 63, q = l >> 4, m = l & 15, mw = m & 7;

  const float* Wih = (dir ? WihB : WihF) + (size_t)c * 384 * 128;
  const float* Whh = (dir ? WhhB : WhhF) + (size_t)c * 384 * 128;
  const float* bih = (dir ? bihB : bihF) + (size_t)c * 384;
  const float* bhh = (dir ? bhhB : bhhF) + (size_t)c * 384;

  __shared__ __align__(16) unsigned x2s[2][64];
  __shared__ __align__(16) unsigned h2s[64];
  __shared__ float aBuf[512];

  h2v wci[8][4], wch[8][4], wsg[8][4];
#pragma unroll
  for (int k = 0; k < 8; ++k) {
    int vc = 32 * w + 8 * q + (k ^ mw);
    const float4* pi = (const float4*)(Wih + (size_t)vc * 128 + 8 * m);
    float4 a = pi[0], b = pi[1];
    wci[k][0] = pk2(a.x, a.y); wci[k][1] = pk2(a.z, a.w);
    wci[k][2] = pk2(b.x, b.y); wci[k][3] = pk2(b.z, b.w);
    const float4* ph = (const float4*)(Whh + (size_t)vc * 128 + 8 * m);
    float4 e = ph[0], f = ph[1];
    wch[k][0] = pk2(e.x, e.y); wch[k][1] = pk2(e.z, e.w);
    wch[k][2] = pk2(f.x, f.y); wch[k][3] = pk2(f.z, f.w);
    int s = (w < 4) ? (32 * w + 8 * q + (k ^ mw)) : (32 * (w - 4) + 8 * q + (k ^ mw));
    const float* sb = (w < 4) ? (Wih + (size_t)(256 + s) * 128) : (Whh + (size_t)(256 + s) * 128);
    const float4* ps = (const float4*)(sb + 8 * m);
    float4 g = ps[0], hh = ps[1];
    wsg[k][0] = pk2(g.x, g.y); wsg[k][1] = pk2(g.z, g.w);
    wsg[k][2] = pk2(hh.x, hh.y); wsg[k][3] = pk2(hh.z, hh.w);
  }
  float bown;
  int ownIdx;
  if (m < 8) {
    int vo = 32 * w + 8 * q + m;
    bown = bih[vo] + bhh[vo];
    ownIdx = vo;
  } else {
    int so = (w < 4) ? (32 * w + 8 * q + mw) : (32 * (w - 4) + 8 * q + mw);
    bown = (w < 4) ? bih[256 + so] : bhh[256 + so];
    ownIdx = (w < 4) ? (256 + so) : (384 + so);
  }

  if (tid < 64) h2s[tid] = 0u;
  if (tid >= 448) {
    int lane = tid - 448;
    x2s[0][lane] = (dir == 0) ? encf2[((size_t)c * 512 + 0) * 64 + lane] : 0x3C003C00u;
  }
  float hreg = 0.f;
  __syncthreads();

  for (int t = 0; t <= 512; ++t) {
    unsigned xpre = 0;
    if (tid >= 448 && t < 512) {  // issue next-x load early; hides under matvec
      int tn = t + 1, lane = tid - 448;
      int row = (dir == 0) ? ((tn < 512) ? tn : -1) : (512 - tn);
      xpre = (row < 0) ? 0x3C003C00u : encf2[((size_t)c * 512 + row) * 64 + lane];
    }
    uint4 xv = ((const uint4*)&x2s[t & 1][0])[m];
    uint4 hv = ((const uint4*)&h2s[0])[m];
    h2v x0 = u2h(xv.x), x1 = u2h(xv.y), x2 = u2h(xv.z), x3 = u2h(xv.w);
    h2v g0 = u2h(hv.x), g1 = u2h(hv.y), g2 = u2h(hv.z), g3 = u2h(hv.w);
    float pA, pB;
    {
      float p[8];
#pragma unroll
      for (int k = 0; k < 8; ++k) {
        float a = 0.f;
        a = fdot2f(wci[k][0], x0, a); a = fdot2f(wci[k][1], x1, a);
        a = fdot2f(wci[k][2], x2, a); a = fdot2f(wci[k][3], x3, a);
        a = fdot2f(wch[k][0], g0, a); a = fdot2f(wch[k][1], g1, a);
        a = fdot2f(wch[k][2], g2, a); a = fdot2f(wch[k][3], g3, a);
        p[k] = a;
      }
      pA = reduce8(p);
    }
    {
      h2v s0 = (w < 4) ? x0 : g0, s1 = (w < 4) ? x1 : g1;
      h2v s2 = (w < 4) ? x2 : g2, s3 = (w < 4) ? x3 : g3;
      float p[8];
#pragma unroll
      for (int k = 0; k < 8; ++k) {
        float a = 0.f;
        a = fdot2f(wsg[k][0], s0, a); a = fdot2f(wsg[k][1], s1, a);
        a = fdot2f(wsg[k][2], s2, a); a = fdot2f(wsg[k][3], s3, a);
        p[k] = a;
      }
      pB = reduce8(p);
    }
    aBuf[ownIdx] = ((m < 8) ? pA : pB) + bown;
    __syncthreads();
    if (tid < 128) {
      float r = sigf(aBuf[tid]);
      float z = sigf(aBuf[128 + tid]);
      float nn = tanhfast(aBuf[256 + tid] + r * aBuf[384 + tid]);
      float hn = (1.f - z) * nn + z * hreg;
      hreg = hn;
      float other = __shfl_xor(hn, 1, 64);
      if ((tid & 1) == 0) h2s[tid >> 1] = h2u(pk2(hn, other));
    } else if (tid >= 448 && t < 512) {
      x2s[(t + 1) & 1][tid - 448] = xpre;
    }
    __syncthreads();
  }
  if (tid < 128) dec_h0[(size_t)c * 256 + dir * 128 + tid] = hreg;
}

// ---------------------------------------------------------------------------
// K5: per-class decoder GRU + fused out-projection + log_softmax.
// 80 blocks x 768 threads (12 waves); wave owns 64 rows; 16-lane group owns
// 16 rows x 16 cols; weights 128 h2v/lane, resident under a 170-VGPR cap.
// ---------------------------------------------------------------------------
__global__ __launch_bounds__(768, 3) void k_dec_gru(
    const float* __restrict__ Whh, const float* __restrict__ bhh,
    const float* __restrict__ gi, const float* __restrict__ h0,
    const int* __restrict__ labels,
    const float* __restrict__ outW, const float* __restrict__ outB,
    float* __restrict__ out) {
  const int c = blockIdx.x, tid = threadIdx.x;
  const int w = tid >> 6, l = tid & 63, q = l >> 4, m = l & 15, mw = m & 7;

  __shared__ __align__(16) unsigned h2s[128];
  __shared__ float aBuf[768];
  __shared__ float gisf[2304];
  __shared__ float owsh[1024];
  __shared__ int labs[513];
  __shared__ float red[4][4];

  h2v wpk[2][8][8];
#pragma unroll
  for (int kc = 0; kc < 2; ++kc)
#pragma unroll
    for (int k = 0; k < 8; ++k) {
      int row = 64 * w + 16 * q + 8 * kc + (k ^ mw);
      const float4* src = (const float4*)(Whh + ((size_t)c * 768 + row) * 256 + 16 * m);
      float4 v0 = src[0], v1 = src[1], v2 = src[2], v3 = src[3];
      wpk[kc][k][0] = pk2(v0.x, v0.y); wpk[kc][k][1] = pk2(v0.z, v0.w);
      wpk[kc][k][2] = pk2(v1.x, v1.y); wpk[kc][k][3] = pk2(v1.z, v1.w);
      wpk[kc][k][4] = pk2(v2.x, v2.y); wpk[kc][k][5] = pk2(v2.z, v2.w);
      wpk[kc][k][6] = pk2(v3.x, v3.y); wpk[kc][k][7] = pk2(v3.z, v3.w);
    }
  float bown = bhh[(size_t)c * 768 + 64 * w + l];

  for (int i = tid; i < 2304; i += 768) gisf[i] = gi[(size_t)c * 4 * 768 + i];
  for (int i = tid; i < 1024; i += 768) owsh[i] = outW[i];
  if (tid < 512) labs[tid + 1] = labels[(size_t)c * 512 + tid];
  if (tid == 512) labs[0] = 2;  // SOS
  float b0 = outB[0], b1 = outB[1], b2 = outB[2], b3 = outB[3];
  float hreg = 0.f;
  if (tid < 256) {
    hreg = h0[(size_t)c * 256 + tid];
    float other = __shfl_xor(hreg, 1, 64);
    if ((tid & 1) == 0) h2s[tid >> 1] = h2u(pk2(hreg, other));
  }
  __syncthreads();

  for (int t = 0; t <= 512; ++t) {
    const uint4* hp = (const uint4*)(&h2s[0]);
    uint4 ha = hp[2 * m], hb = hp[2 * m + 1];
    h2v g0 = u2h(ha.x), g1 = u2h(ha.y), g2 = u2h(ha.z), g3 = u2h(ha.w);
    h2v g4 = u2h(hb.x), g5 = u2h(hb.y), g6 = u2h(hb.z), g7 = u2h(hb.w);
    float pc0, pc1;
    {
      float p[8];
#pragma unroll
      for (int k = 0; k < 8; ++k) {
        float a = 0.f;
        a = fdot2f(wpk[0][k][0], g0, a); a = fdot2f(wpk[0][k][1], g1, a);
        a = fdot2f(wpk[0][k][2], g2, a); a = fdot2f(wpk[0][k][3], g3, a);
        a = fdot2f(wpk[0][k][4], g4, a); a = fdot2f(wpk[0][k][5], g5, a);
        a = fdot2f(wpk[0][k][6], g6, a); a = fdot2f(wpk[0][k][7], g7, a);
        p[k] = a;
      }
      pc0 = reduce8(p);
    }
    {
      float p[8];
#pragma unroll
      for (int k = 0; k < 8; ++k) {
        float a = 0.f;
        a = fdot2f(wpk[1][k][0], g0, a); a = fdot2f(wpk[1][k][1], g1, a);
        a = fdot2f(wpk[1][k][2], g2, a); a = fdot2f(wpk[1][k][3], g3, a);
        a = fdot2f(wpk[1][k][4], g4, a); a = fdot2f(wpk[1][k][5], g5, a);
        a = fdot2f(wpk[1][k][6], g6, a); a = fdot2f(wpk[1][k][7], g7, a);
        p[k] = a;
      }
      pc1 = reduce8(p);
    }
    aBuf[64 * w + l] = ((m < 8) ? pc0 : pc1) + bown;
    __syncthreads();
    if (tid < 256) {
      int sel = labs[t];
      const float* gsel = &gisf[sel * 768];
      float r = sigf(gsel[tid] + aBuf[tid]);
      float z = sigf(gsel[256 + tid] + aBuf[256 + tid]);
      float nn = tanhfast(gsel[512 + tid] + r * aBuf[512 + tid]);
      float hn = (1.f - z) * nn + z * hreg;
      hreg = hn;
      float other = __shfl_xor(hn, 1, 64);
      if ((tid & 1) == 0) h2s[tid >> 1] = h2u(pk2(hn, other));
      float p0 = owsh[tid] * hn, p1 = owsh[256 + tid] * hn;
      float p2 = owsh[512 + tid] * hn, p3 = owsh[768 + tid] * hn;
#pragma unroll
      for (int off = 32; off > 0; off >>= 1) {
        p0 += __shfl_xor(p0, off, 64);
        p1 += __shfl_xor(p1, off, 64);
        p2 += __shfl_xor(p2, off, 64);
        p3 += __shfl_xor(p3, off, 64);
      }
      if ((tid & 63) == 0) {
        int ww = tid >> 6;
        red[ww][0] = p0; red[ww][1] = p1; red[ww][2] = p2; red[ww][3] = p3;
      }
    }
    __syncthreads();
    if (tid == 0) {
      float l0 = red[0][0] + red[1][0] + red[2][0] + red[3][0] + b0;
      float l1 = red[0][1] + red[1][1] + red[2][1] + red[3][1] + b1;
      float l2 = red[0][2] + red[1][2] + red[2][2] + red[3][2] + b2;
      float l3 = red[0][3] + red[1][3] + red[2][3] + red[3][3] + b3;
      float mm = fmaxf(fmaxf(l0, l1), fmaxf(l2, l3));
      float s = __expf(l0 - mm) + __expf(l1 - mm) + __expf(l2 - mm) + __expf(l3 - mm);
      float lse = mm + __logf(s);
      float* o = out + ((size_t)c * 513 + t) * 4;
      o[0] = l0 - lse; o[1] = l1 - lse; o[2] = l2 - lse; o[3] = l3 - lse;
    }
  }
}

// ---------------------------------------------------------------------------
// K6: labels (as float) and weights passthrough
// ---------------------------------------------------------------------------
__global__ void k_passthrough(const int* __restrict__ labels,
                              const float* __restrict__ weights,
                              float* __restrict__ out) {
  int i = blockIdx.x * blockDim.x + threadIdx.x;
  if (i < 40960) {
    out[164160 + i] = (float)labels[i];
    out[164160 + 40960 + i] = weights[i];
  }
}

// ---------------------------------------------------------------------------
extern "C" void kernel_launch(void* const* d_in, const int* in_sizes, int n_in,
                              void* d_out, int out_size, void* d_ws, size_t ws_size,
                              hipStream_t stream) {
  (void)in_sizes; (void)n_in; (void)out_size; (void)ws_size;
  const float* feat = (const float*)d_in[0];
  const float* score = (const float*)d_in[1];
  const float* box = (const float*)d_in[2];
  const float* orig = (const float*)d_in[3];
  const int* labels = (const int*)d_in[4];
  const float* weights = (const float*)d_in[5];
  const float* appear_W = (const float*)d_in[8];
  const float* appear_b = (const float*)d_in[9];
  const float* featlin_W = (const float*)d_in[10];
  const float* featlin_b = (const float*)d_in[11];
  const float* eWihF = (const float*)d_in[12];
  const float* eWhhF = (const float*)d_in[13];
  const float* ebihF = (const float*)d_in[14];
  const float* ebhhF = (const float*)d_in[15];
  const float* eWihB = (const float*)d_in[16];
  const float* eWhhB = (const float*)d_in[17];
  const float* ebihB = (const float*)d_in[18];
  const float* ebhhB = (const float*)d_in[19];
  const float* dec_emb = (const float*)d_in[20];
  const float* dWih = (const float*)d_in[21];
  const float* dWhh = (const float*)d_in[22];
  const float* dbih = (const float*)d_in[23];
  const float* dbhh = (const float*)d_in[24];
  const float* outW = (const float*)d_in[25];
  const float* outB = (const float*)d_in[26];
  float* out = (float*)d_out;

  char* ws = (char*)d_ws;
  float* allf = (float*)ws;                                     // 40960*224 f32
  unsigned* encf2 = (unsigned*)(ws + (size_t)40960 * 224 * 4);  // 40960*64 u32
  float* dec_h0 = (float*)(ws + (size_t)40960 * 224 * 4 + (size_t)40960 * 64 * 4);
  float* dec_gi = dec_h0 + 80 * 256;                            // 80*4*768 f32

  k_fill_misc<<<15360, 256, 0, stream>>>(score, box, orig, allf);
  k_gemm_appear<<<640, 256, 0, stream>>>(feat, appear_W, appear_b, allf);
  k_gemm_featlin<<<640, 256, 0, stream>>>(allf, featlin_W, featlin_b, encf2);
  k_dec_gi<<<80, 256, 0, stream>>>(dWih, dbih, dec_emb, dec_gi);
  k_enc_gru<<<160, 512, 0, stream>>>(encf2, eWihF, eWhhF, ebihF, ebhhF,
                                     eWihB, eWhhB, ebihB, ebhhB, dec_h0);
  k_dec_gru<<<80, 768, 0, stream>>>(dWhh, dbhh, dec_gi, dec_h0, labels, outW, outB, out);
  k_passthrough<<<160, 256, 0, stream>>>(labels, weights, out);
}

// Round 4
// 1648.887 us; speedup vs baseline: 1.0106x; 1.0021x over previous
//
#include <hip/hip_runtime.h>

// ---------------------------------------------------------------------------
// Encoder_Decoder: 80-class bidirectional GRU encoder (H=128) + GRU decoder
// (DH=256) with teacher forcing, plus two shared dense layers.
// v4: same structure as v3 (column-partitioned matvec, weights in VGPRs as
// f16x2, DPP/ds_swizzle xor-butterfly reduce), but with
// amdgpu_waves_per_eu(min,max) pinned so the allocator actually KEEPS the
// weight arrays resident (v2/v3 spilled: VGPR_Count=84, 27 MB scratch writes).
//   k_dec_gru: 12 waves/block -> (3,3): budget ~168 VGPR, need ~160.
//   k_enc_gru:  8 waves/block -> (2,2): budget 256 VGPR, need ~140.
// ---------------------------------------------------------------------------

typedef __fp16 h2v __attribute__((ext_vector_type(2)));

__device__ __forceinline__ h2v pk2(float a, float b) {
  return __builtin_amdgcn_cvt_pkrtz(a, b);
}
__device__ __forceinline__ unsigned h2u(h2v h) { return __builtin_bit_cast(unsigned, h); }
__device__ __forceinline__ h2v u2h(unsigned u) { return __builtin_bit_cast(h2v, u); }
__device__ __forceinline__ float fdot2f(h2v a, h2v b, float c) {
  return __builtin_amdgcn_fdot2(a, b, c, false);
}
__device__ __forceinline__ float sigf(float x) { return 1.f / (1.f + __expf(-x)); }
__device__ __forceinline__ float tanhfast(float x) { return 2.f / (1.f + __expf(-2.f * x)) - 1.f; }

// acc + (partner-lane v) via DPP. CTRL: 0xB1 = quad_perm[1,0,3,2] (xor1),
// 0x4E = quad_perm[2,3,0,1] (xor2), 0x128 = row_ror:8 (xor8 within 16-row).
template <int CTRL>
__device__ __forceinline__ float dppadd(float acc, float v) {
  int r = __builtin_amdgcn_update_dpp(0, __float_as_int(v), CTRL, 0xF, 0xF, true);
  return acc + __int_as_float(r);
}
// xor-4 via ds_swizzle BitMode: (4<<10)|0x1F
__device__ __forceinline__ float swz4add(float acc, float v) {
  return acc + __int_as_float(__builtin_amdgcn_ds_swizzle(__float_as_int(v), 0x101F));
}

// Reduce 8 partials (slot k on lane holds row-id k^(m&7)) across a 16-lane
// group; returns the full sum for row-id (m&7) (identical on lanes m, m^8).
__device__ __forceinline__ float reduce8(float p[8]) {
  p[0] = dppadd<0xB1>(p[0], p[1]);
  p[2] = dppadd<0xB1>(p[2], p[3]);
  p[4] = dppadd<0xB1>(p[4], p[5]);
  p[6] = dppadd<0xB1>(p[6], p[7]);
  p[0] = dppadd<0x4E>(p[0], p[2]);
  p[4] = dppadd<0x4E>(p[4], p[6]);
  p[0] = swz4add(p[0], p[4]);
  p[0] = dppadd<0x128>(p[0], p[0]);
  return p[0];
}

// ---------------------------------------------------------------------------
// K0: fill allf[:,128:224] with score|box|origin_score
// ---------------------------------------------------------------------------
__global__ void k_fill_misc(const float* __restrict__ score, const float* __restrict__ box,
                            const float* __restrict__ orig, float* __restrict__ allf) {
  int i = blockIdx.x * blockDim.x + threadIdx.x;
  if (i >= 40960 * 96) return;
  int row = i / 96, k = i - row * 96;
  float v;
  if (k == 0) v = score[row];
  else if (k < 5) v = box[row * 4 + (k - 1)];
  else v = orig[(size_t)row * 91 + (k - 5)];
  allf[(size_t)row * 224 + 128 + k] = v;
}

// ---------------------------------------------------------------------------
// K1: allf[:,0:128] = relu(feat @ appear_W^T + appear_b)
// ---------------------------------------------------------------------------
__global__ __launch_bounds__(256) void k_gemm_appear(
    const float* __restrict__ A, const float* __restrict__ W,
    const float* __restrict__ bias, float* __restrict__ allf) {
  __shared__ float As[32][68];
  __shared__ float Ws[32][132];
  const int tid = threadIdx.x;
  const int tx = tid & 15, ty = tid >> 4;
  const int r0 = blockIdx.x * 64;
  const int lr = tid >> 3;
  const int lk = (tid & 7) * 4;
  float acc[4][8];
#pragma unroll
  for (int i = 0; i < 4; ++i)
#pragma unroll
    for (int j = 0; j < 8; ++j) acc[i][j] = 0.f;

  for (int k0 = 0; k0 < 1024; k0 += 32) {
#pragma unroll
    for (int i = 0; i < 2; ++i) {
      int rr = lr + i * 32;
      float4 v = *(const float4*)(A + (size_t)(r0 + rr) * 1024 + k0 + lk);
      As[lk + 0][rr] = v.x; As[lk + 1][rr] = v.y; As[lk + 2][rr] = v.z; As[lk + 3][rr] = v.w;
    }
#pragma unroll
    for (int i = 0; i < 4; ++i) {
      int wr = lr + i * 32;
      float4 v = *(const float4*)(W + (size_t)wr * 1024 + k0 + lk);
      Ws[lk + 0][wr] = v.x; Ws[lk + 1][wr] = v.y; Ws[lk + 2][wr] = v.z; Ws[lk + 3][wr] = v.w;
    }
    __syncthreads();
#pragma unroll
    for (int kk = 0; kk < 32; ++kk) {
      float4 a = *(const float4*)&As[kk][ty * 4];
      float4 w0 = *(const float4*)&Ws[kk][tx * 8];
      float4 w1 = *(const float4*)&Ws[kk][tx * 8 + 4];
      float av[4] = {a.x, a.y, a.z, a.w};
      float wv[8] = {w0.x, w0.y, w0.z, w0.w, w1.x, w1.y, w1.z, w1.w};
#pragma unroll
      for (int i = 0; i < 4; ++i)
#pragma unroll
        for (int j = 0; j < 8; ++j) acc[i][j] = fmaf(av[i], wv[j], acc[i][j]);
    }
    __syncthreads();
  }
#pragma unroll
  for (int i = 0; i < 4; ++i) {
    int row = r0 + ty * 4 + i;
#pragma unroll
    for (int j = 0; j < 8; ++j) {
      int col = tx * 8 + j;
      float v = acc[i][j] + bias[col];
      allf[(size_t)row * 224 + col] = fmaxf(v, 0.f);
    }
  }
}

// ---------------------------------------------------------------------------
// K2: enc_feat = relu(allf @ featlin_W^T + b), stored packed f16x2
// ---------------------------------------------------------------------------
__global__ __launch_bounds__(256) void k_gemm_featlin(
    const float* __restrict__ A, const float* __restrict__ W,
    const float* __restrict__ bias, unsigned* __restrict__ encf2) {
  __shared__ float As[32][68];
  __shared__ float Ws[32][132];
  const int tid = threadIdx.x;
  const int tx = tid & 15, ty = tid >> 4;
  const int r0 = blockIdx.x * 64;
  const int lr = tid >> 3;
  const int lk = (tid & 7) * 4;
  float acc[4][8];
#pragma unroll
  for (int i = 0; i < 4; ++i)
#pragma unroll
    for (int j = 0; j < 8; ++j) acc[i][j] = 0.f;

  for (int k0 = 0; k0 < 224; k0 += 32) {
#pragma unroll
    for (int i = 0; i < 2; ++i) {
      int rr = lr + i * 32;
      float4 v = *(const float4*)(A + (size_t)(r0 + rr) * 224 + k0 + lk);
      As[lk + 0][rr] = v.x; As[lk + 1][rr] = v.y; As[lk + 2][rr] = v.z; As[lk + 3][rr] = v.w;
    }
#pragma unroll
    for (int i = 0; i < 4; ++i) {
      int wr = lr + i * 32;
      float4 v = *(const float4*)(W + (size_t)wr * 224 + k0 + lk);
      Ws[lk + 0][wr] = v.x; Ws[lk + 1][wr] = v.y; Ws[lk + 2][wr] = v.z; Ws[lk + 3][wr] = v.w;
    }
    __syncthreads();
#pragma unroll
    for (int kk = 0; kk < 32; ++kk) {
      float4 a = *(const float4*)&As[kk][ty * 4];
      float4 w0 = *(const float4*)&Ws[kk][tx * 8];
      float4 w1 = *(const float4*)&Ws[kk][tx * 8 + 4];
      float av[4] = {a.x, a.y, a.z, a.w};
      float wv[8] = {w0.x, w0.y, w0.z, w0.w, w1.x, w1.y, w1.z, w1.w};
#pragma unroll
      for (int i = 0; i < 4; ++i)
#pragma unroll
        for (int j = 0; j < 8; ++j) acc[i][j] = fmaf(av[i], wv[j], acc[i][j]);
    }
    __syncthreads();
  }
#pragma unroll
  for (int i = 0; i < 4; ++i) {
    int row = r0 + ty * 4 + i;
    unsigned* orow = encf2 + (size_t)row * 64;
#pragma unroll
    for (int p = 0; p < 4; ++p) {
      int col = tx * 8 + 2 * p;
      float a = fmaxf(acc[i][2 * p] + bias[col], 0.f);
      float b = fmaxf(acc[i][2 * p + 1] + bias[col + 1], 0.f);
      orow[tx * 4 + p] = h2u(pk2(a, b));
    }
  }
}

// ---------------------------------------------------------------------------
// K3: decoder input projections: gi[c][v][r] = dec_Wih[c][r]@dec_emb[v] + bih
// ---------------------------------------------------------------------------
__global__ __launch_bounds__(256) void k_dec_gi(
    const float* __restrict__ Wih, const float* __restrict__ bih,
    const float* __restrict__ emb, float* __restrict__ gi) {
  __shared__ float e[4][32];
  const int c = blockIdx.x, tid = threadIdx.x;
  if (tid < 128) e[tid >> 5][tid & 31] = emb[tid];
  __syncthreads();
#pragma unroll
  for (int i = 0; i < 3; ++i) {
    int r = tid + i * 256;
    const float* w = Wih + ((size_t)c * 768 + r) * 32;
    float b = bih[(size_t)c * 768 + r];
    float a0 = b, a1 = b, a2 = b, a3 = b;
#pragma unroll
    for (int k = 0; k < 32; ++k) {
      float wv = w[k];
      a0 = fmaf(wv, e[0][k], a0);
      a1 = fmaf(wv, e[1][k], a1);
      a2 = fmaf(wv, e[2][k], a2);
      a3 = fmaf(wv, e[3][k], a3);
    }
    gi[((size_t)c * 4 + 0) * 768 + r] = a0;
    gi[((size_t)c * 4 + 1) * 768 + r] = a1;
    gi[((size_t)c * 4 + 2) * 768 + r] = a2;
    gi[((size_t)c * 4 + 3) * 768 + r] = a3;
  }
}

// ---------------------------------------------------------------------------
// K4: per-(class,dir) encoder GRU, 513 steps. 160 blocks x 512 threads.
// 8 waves; each wave: 32 combined r/z rows (Wih·x + Whh·h fused) + 32 single
// rows (i_n for w<4, h_n for w>=4). 16-lane group owns 16 rows x 8 cols.
// waves_per_eu(2,2): 8-wave block = 2 waves/SIMD, 1 block/CU, 256-VGPR budget
// so the 96 weight regs stay resident (v3 spilled them).
// ---------------------------------------------------------------------------
__global__ __launch_bounds__(512)
__attribute__((amdgpu_waves_per_eu(2, 2))) void k_enc_gru(
    const unsigned* __restrict__ encf2,
    const float* __restrict__ WihF, const float* __restrict__ WhhF,
    const float* __restrict__ bihF, const float* __restrict__ bhhF,
    const float* __restrict__ WihB, const float* __restrict__ WhhB,
    const float* __restrict__ bihB, const float* __restrict__ bhhB,
    float* __restrict__ dec_h0) {
  const int blk = blockIdx.x;
  const int c = blk >> 1, dir = blk & 1;
  const int tid = threadIdx.x;
  const int w = tid >> 6, l = tid & 63, q = l >> 4, m = l & 15, mw = m & 7;

  const float* Wih = (dir ? WihB : WihF) + (size_t)c * 384 * 128;
  const float* Whh = (dir ? WhhB : WhhF) + (size_t)c * 384 * 128;
  const float* bih = (dir ? bihB : bihF) + (size_t)c * 384;
  const float* bhh = (dir ? bhhB : bhhF) + (size_t)c * 384;

  __shared__ __align__(16) unsigned x2s[2][64];
  __shared__ __align__(16) unsigned h2s[64];
  __shared__ float aBuf[512];

  h2v wci[8][4], wch[8][4], wsg[8][4];
#pragma unroll
  for (int k = 0; k < 8; ++k) {
    int vc = 32 * w + 8 * q + (k ^ mw);
    const float4* pi = (const float4*)(Wih + (size_t)vc * 128 + 8 * m);
    float4 a = pi[0], b = pi[1];
    wci[k][0] = pk2(a.x, a.y); wci[k][1] = pk2(a.z, a.w);
    wci[k][2] = pk2(b.x, b.y); wci[k][3] = pk2(b.z, b.w);
    const float4* ph = (const float4*)(Whh + (size_t)vc * 128 + 8 * m);
    float4 e = ph[0], f = ph[1];
    wch[k][0] = pk2(e.x, e.y); wch[k][1] = pk2(e.z, e.w);
    wch[k][2] = pk2(f.x, f.y); wch[k][3] = pk2(f.z, f.w);
    int s = (w < 4) ? (32 * w + 8 * q + (k ^ mw)) : (32 * (w - 4) + 8 * q + (k ^ mw));
    const float* sb = (w < 4) ? (Wih + (size_t)(256 + s) * 128) : (Whh + (size_t)(256 + s) * 128);
    const float4* ps = (const float4*)(sb + 8 * m);
    float4 g = ps[0], hh = ps[1];
    wsg[k][0] = pk2(g.x, g.y); wsg[k][1] = pk2(g.z, g.w);
    wsg[k][2] = pk2(hh.x, hh.y); wsg[k][3] = pk2(hh.z, hh.w);
  }
  float bown;
  int ownIdx;
  if (m < 8) {
    int vo = 32 * w + 8 * q + m;
    bown = bih[vo] + bhh[vo];
    ownIdx = vo;
  } else {
    int so = (w < 4) ? (32 * w + 8 * q + mw) : (32 * (w - 4) + 8 * q + mw);
    bown = (w < 4) ? bih[256 + so] : bhh[256 + so];
    ownIdx = (w < 4) ? (256 + so) : (384 + so);
  }

  if (tid < 64) h2s[tid] = 0u;
  if (tid >= 448) {
    int lane = tid - 448;
    x2s[0][lane] = (dir == 0) ? encf2[((size_t)c * 512 + 0) * 64 + lane] : 0x3C003C00u;
  }
  float hreg = 0.f;
  __syncthreads();

  for (int t = 0; t <= 512; ++t) {
    unsigned xpre = 0;
    if (tid >= 448 && t < 512) {  // issue next-x load early; hides under matvec
      int tn = t + 1, lane = tid - 448;
      int row = (dir == 0) ? ((tn < 512) ? tn : -1) : (512 - tn);
      xpre = (row < 0) ? 0x3C003C00u : encf2[((size_t)c * 512 + row) * 64 + lane];
    }
    uint4 xv = ((const uint4*)&x2s[t & 1][0])[m];
    uint4 hv = ((const uint4*)&h2s[0])[m];
    h2v x0 = u2h(xv.x), x1 = u2h(xv.y), x2 = u2h(xv.z), x3 = u2h(xv.w);
    h2v g0 = u2h(hv.x), g1 = u2h(hv.y), g2 = u2h(hv.z), g3 = u2h(hv.w);
    float pA, pB;
    {
      float p[8];
#pragma unroll
      for (int k = 0; k < 8; ++k) {
        float a = 0.f;
        a = fdot2f(wci[k][0], x0, a); a = fdot2f(wci[k][1], x1, a);
        a = fdot2f(wci[k][2], x2, a); a = fdot2f(wci[k][3], x3, a);
        a = fdot2f(wch[k][0], g0, a); a = fdot2f(wch[k][1], g1, a);
        a = fdot2f(wch[k][2], g2, a); a = fdot2f(wch[k][3], g3, a);
        p[k] = a;
      }
      pA = reduce8(p);
    }
    {
      h2v s0 = (w < 4) ? x0 : g0, s1 = (w < 4) ? x1 : g1;
      h2v s2 = (w < 4) ? x2 : g2, s3 = (w < 4) ? x3 : g3;
      float p[8];
#pragma unroll
      for (int k = 0; k < 8; ++k) {
        float a = 0.f;
        a = fdot2f(wsg[k][0], s0, a); a = fdot2f(wsg[k][1], s1, a);
        a = fdot2f(wsg[k][2], s2, a); a = fdot2f(wsg[k][3], s3, a);
        p[k] = a;
      }
      pB = reduce8(p);
    }
    aBuf[ownIdx] = ((m < 8) ? pA : pB) + bown;
    __syncthreads();
    if (tid < 128) {
      float r = sigf(aBuf[tid]);
      float z = sigf(aBuf[128 + tid]);
      float nn = tanhfast(aBuf[256 + tid] + r * aBuf[384 + tid]);
      float hn = (1.f - z) * nn + z * hreg;
      hreg = hn;
      float other = __shfl_xor(hn, 1, 64);
      if ((tid & 1) == 0) h2s[tid >> 1] = h2u(pk2(hn, other));
    } else if (tid >= 448 && t < 512) {
      x2s[(t + 1) & 1][tid - 448] = xpre;
    }
    __syncthreads();
  }
  if (tid < 128) dec_h0[(size_t)c * 256 + dir * 128 + tid] = hreg;
}

// ---------------------------------------------------------------------------
// K5: per-class decoder GRU + fused out-projection + log_softmax.
// 80 blocks x 768 threads (12 waves = 3 waves/SIMD); wave owns 64 rows;
// 16-lane group owns 16 rows x 16 cols; 128 weight h2v per lane.
// waves_per_eu(3,3): 1 block/CU, ~168-VGPR budget -> weights resident.
// ---------------------------------------------------------------------------
__global__ __launch_bounds__(768)
__attribute__((amdgpu_waves_per_eu(3, 3))) void k_dec_gru(
    const float* __restrict__ Whh, const float* __restrict__ bhh,
    const float* __restrict__ gi, const float* __restrict__ h0,
    const int* __restrict__ labels,
    const float* __restrict__ outW, const float* __restrict__ outB,
    float* __restrict__ out) {
  const int c = blockIdx.x, tid = threadIdx.x;
  const int w = tid >> 6, l = tid & 63, q = l >> 4, m = l & 15, mw = m & 7;

  __shared__ __align__(16) unsigned h2s[128];
  __shared__ float aBuf[768];
  __shared__ float gisf[2304];
  __shared__ float owsh[1024];
  __shared__ int labs[513];
  __shared__ float red[4][4];

  h2v wpk[2][8][8];
#pragma unroll
  for (int kc = 0; kc < 2; ++kc)
#pragma unroll
    for (int k = 0; k < 8; ++k) {
      int row = 64 * w + 16 * q + 8 * kc + (k ^ mw);
      const float4* src = (const float4*)(Whh + ((size_t)c * 768 + row) * 256 + 16 * m);
      float4 v0 = src[0], v1 = src[1], v2 = src[2], v3 = src[3];
      wpk[kc][k][0] = pk2(v0.x, v0.y); wpk[kc][k][1] = pk2(v0.z, v0.w);
      wpk[kc][k][2] = pk2(v1.x, v1.y); wpk[kc][k][3] = pk2(v1.z, v1.w);
      wpk[kc][k][4] = pk2(v2.x, v2.y); wpk[kc][k][5] = pk2(v2.z, v2.w);
      wpk[kc][k][6] = pk2(v3.x, v3.y); wpk[kc][k][7] = pk2(v3.z, v3.w);
    }
  float bown = bhh[(size_t)c * 768 + 64 * w + l];

  for (int i = tid; i < 2304; i += 768) gisf[i] = gi[(size_t)c * 4 * 768 + i];
  for (int i = tid; i < 1024; i += 768) owsh[i] = outW[i];
  if (tid < 512) labs[tid + 1] = labels[(size_t)c * 512 + tid];
  if (tid == 512) labs[0] = 2;  // SOS
  float b0 = outB[0], b1 = outB[1], b2 = outB[2], b3 = outB[3];
  float hreg = 0.f;
  if (tid < 256) {
    hreg = h0[(size_t)c * 256 + tid];
    float other = __shfl_xor(hreg, 1, 64);
    if ((tid & 1) == 0) h2s[tid >> 1] = h2u(pk2(hreg, other));
  }
  __syncthreads();

  for (int t = 0; t <= 512; ++t) {
    const uint4* hp = (const uint4*)(&h2s[0]);
    uint4 ha = hp[2 * m], hb = hp[2 * m + 1];
    h2v g0 = u2h(ha.x), g1 = u2h(ha.y), g2 = u2h(ha.z), g3 = u2h(ha.w);
    h2v g4 = u2h(hb.x), g5 = u2h(hb.y), g6 = u2h(hb.z), g7 = u2h(hb.w);
    float pc0, pc1;
    {
      float p[8];
#pragma unroll
      for (int k = 0; k < 8; ++k) {
        float a = 0.f;
        a = fdot2f(wpk[0][k][0], g0, a); a = fdot2f(wpk[0][k][1], g1, a);
        a = fdot2f(wpk[0][k][2], g2, a); a = fdot2f(wpk[0][k][3], g3, a);
        a = fdot2f(wpk[0][k][4], g4, a); a = fdot2f(wpk[0][k][5], g5, a);
        a = fdot2f(wpk[0][k][6], g6, a); a = fdot2f(wpk[0][k][7], g7, a);
        p[k] = a;
      }
      pc0 = reduce8(p);
    }
    {
      float p[8];
#pragma unroll
      for (int k = 0; k < 8; ++k) {
        float a = 0.f;
        a = fdot2f(wpk[1][k][0], g0, a); a = fdot2f(wpk[1][k][1], g1, a);
        a = fdot2f(wpk[1][k][2], g2, a); a = fdot2f(wpk[1][k][3], g3, a);
        a = fdot2f(wpk[1][k][4], g4, a); a = fdot2f(wpk[1][k][5], g5, a);
        a = fdot2f(wpk[1][k][6], g6, a); a = fdot2f(wpk[1][k][7], g7, a);
        p[k] = a;
      }
      pc1 = reduce8(p);
    }
    aBuf[64 * w + l] = ((m < 8) ? pc0 : pc1) + bown;
    __syncthreads();
    if (tid < 256) {
      int sel = labs[t];
      const float* gsel = &gisf[sel * 768];
      float r = sigf(gsel[tid] + aBuf[tid]);
      float z = sigf(gsel[256 + tid] + aBuf[256 + tid]);
      float nn = tanhfast(gsel[512 + tid] + r * aBuf[512 + tid]);
      float hn = (1.f - z) * nn + z * hreg;
      hreg = hn;
      float other = __shfl_xor(hn, 1, 64);
      if ((tid & 1) == 0) h2s[tid >> 1] = h2u(pk2(hn, other));
      float p0 = owsh[tid] * hn, p1 = owsh[256 + tid] * hn;
      float p2 = owsh[512 + tid] * hn, p3 = owsh[768 + tid] * hn;
#pragma unroll
      for (int off = 32; off > 0; off >>= 1) {
        p0 += __shfl_xor(p0, off, 64);
        p1 += __shfl_xor(p1, off, 64);
        p2 += __shfl_xor(p2, off, 64);
        p3 += __shfl_xor(p3, off, 64);
      }
      if ((tid & 63) == 0) {
        int ww = tid >> 6;
        red[ww][0] = p0; red[ww][1] = p1; red[ww][2] = p2; red[ww][3] = p3;
      }
    }
    __syncthreads();
    if (tid == 0) {
      float l0 = red[0][0] + red[1][0] + red[2][0] + red[3][0] + b0;
      float l1 = red[0][1] + red[1][1] + red[2][1] + red[3][1] + b1;
      float l2 = red[0][2] + red[1][2] + red[2][2] + red[3][2] + b2;
      float l3 = red[0][3] + red[1][3] + red[2][3] + red[3][3] + b3;
      float mm = fmaxf(fmaxf(l0, l1), fmaxf(l2, l3));
      float s = __expf(l0 - mm) + __expf(l1 - mm) + __expf(l2 - mm) + __expf(l3 - mm);
      float lse = mm + __logf(s);
      float* o = out + ((size_t)c * 513 + t) * 4;
      o[0] = l0 - lse; o[1] = l1 - lse; o[2] = l2 - lse; o[3] = l3 - lse;
    }
  }
}

// ---------------------------------------------------------------------------
// K6: labels (as float) and weights passthrough
// ---------------------------------------------------------------------------
__global__ void k_passthrough(const int* __restrict__ labels,
                              const float* __restrict__ weights,
                              float* __restrict__ out) {
  int i = blockIdx.x * blockDim.x + threadIdx.x;
  if (i < 40960) {
    out[164160 + i] = (float)labels[i];
    out[164160 + 40960 + i] = weights[i];
  }
}

// ---------------------------------------------------------------------------
extern "C" void kernel_launch(void* const* d_in, const int* in_sizes, int n_in,
                              void* d_out, int out_size, void* d_ws, size_t ws_size,
                              hipStream_t stream) {
  (void)in_sizes; (void)n_in; (void)out_size; (void)ws_size;
  const float* feat = (const float*)d_in[0];
  const float* score = (const float*)d_in[1];
  const float* box = (const float*)d_in[2];
  const float* orig = (const float*)d_in[3];
  const int* labels = (const int*)d_in[4];
  const float* weights = (const float*)d_in[5];
  const float* appear_W = (const float*)d_in[8];
  const float* appear_b = (const float*)d_in[9];
  const float* featlin_W = (const float*)d_in[10];
  const float* featlin_b = (const float*)d_in[11];
  const float* eWihF = (const float*)d_in[12];
  const float* eWhhF = (const float*)d_in[13];
  const float* ebihF = (const float*)d_in[14];
  const float* ebhhF = (const float*)d_in[15];
  const float* eWihB = (const float*)d_in[16];
  const float* eWhhB = (const float*)d_in[17];
  const float* ebihB = (const float*)d_in[18];
  const float* ebhhB = (const float*)d_in[19];
  const float* dec_emb = (const float*)d_in[20];
  const float* dWih = (const float*)d_in[21];
  const float* dWhh = (const float*)d_in[22];
  const float* dbih = (const float*)d_in[23];
  const float* dbhh = (const float*)d_in[24];
  const float* outW = (const float*)d_in[25];
  const float* outB = (const float*)d_in[26];
  float* out = (float*)d_out;

  char* ws = (char*)d_ws;
  float* allf = (float*)ws;                                     // 40960*224 f32
  unsigned* encf2 = (unsigned*)(ws + (size_t)40960 * 224 * 4);  // 40960*64 u32
  float* dec_h0 = (float*)(ws + (size_t)40960 * 224 * 4 + (size_t)40960 * 64 * 4);
  float* dec_gi = dec_h0 + 80 * 256;                            // 80*4*768 f32

  k_fill_misc<<<15360, 256, 0, stream>>>(score, box, orig, allf);
  k_gemm_appear<<<640, 256, 0, stream>>>(feat, appear_W, appear_b, allf);
  k_gemm_featlin<<<640, 256, 0, stream>>>(allf, featlin_W, featlin_b, encf2);
  k_dec_gi<<<80, 256, 0, stream>>>(dWih, dbih, dec_emb, dec_gi);
  k_enc_gru<<<160, 512, 0, stream>>>(encf2, eWihF, eWhhF, ebihF, ebhhF,
                                     eWihB, eWhhB, ebihB, ebhhB, dec_h0);
  k_dec_gru<<<80, 768, 0, stream>>>(dWhh, dbhh, dec_gi, dec_h0, labels, outW, outB, out);
  k_passthrough<<<160, 256, 0, stream>>>(labels, weights, out);
}

// Round 5
// 1647.936 us; speedup vs baseline: 1.0112x; 1.0006x over previous
//
#include <hip/hip_runtime.h>

// ---------------------------------------------------------------------------
// Encoder_Decoder: 80-class bidirectional GRU encoder (H=128) + GRU decoder
// (DH=256) with teacher forcing, plus two shared dense layers.
// v5: v4 + sched_barrier(0)-fenced weight-load prologues. v3/v4 spilled the
// register-resident weight arrays NOT because the budget was too small but
// because the fully-unrolled load+convert prologue let the scheduler hoist
// ~64 in-flight float4 loads on top of the partially-built weight array,
// overflowing the 170-VGPR budget; RA then spilled the whole long-lived
// array (VGPR_Count=84, 26 MB scratch writes, L2-bound 970us loop).
// Fencing each row's load+convert caps in-flight pressure at ~16 regs.
// ---------------------------------------------------------------------------

typedef __fp16 h2v __attribute__((ext_vector_type(2)));

__device__ __forceinline__ h2v pk2(float a, float b) {
  return __builtin_amdgcn_cvt_pkrtz(a, b);
}
__device__ __forceinline__ unsigned h2u(h2v h) { return __builtin_bit_cast(unsigned, h); }
__device__ __forceinline__ h2v u2h(unsigned u) { return __builtin_bit_cast(h2v, u); }
__device__ __forceinline__ float fdot2f(h2v a, h2v b, float c) {
  return __builtin_amdgcn_fdot2(a, b, c, false);
}
__device__ __forceinline__ float sigf(float x) { return 1.f / (1.f + __expf(-x)); }
__device__ __forceinline__ float tanhfast(float x) { return 2.f / (1.f + __expf(-2.f * x)) - 1.f; }

// acc + (partner-lane v) via DPP. CTRL: 0xB1 = quad_perm[1,0,3,2] (xor1),
// 0x4E = quad_perm[2,3,0,1] (xor2), 0x128 = row_ror:8 (xor8 within 16-row).
template <int CTRL>
__device__ __forceinline__ float dppadd(float acc, float v) {
  int r = __builtin_amdgcn_update_dpp(0, __float_as_int(v), CTRL, 0xF, 0xF, true);
  return acc + __int_as_float(r);
}
// xor-4 via ds_swizzle BitMode: (4<<10)|0x1F
__device__ __forceinline__ float swz4add(float acc, float v) {
  return acc + __int_as_float(__builtin_amdgcn_ds_swizzle(__float_as_int(v), 0x101F));
}

// Reduce 8 partials (slot k on lane holds row-id k^(m&7)) across a 16-lane
// group; returns the full sum for row-id (m&7) (identical on lanes m, m^8).
__device__ __forceinline__ float reduce8(float p[8]) {
  p[0] = dppadd<0xB1>(p[0], p[1]);
  p[2] = dppadd<0xB1>(p[2], p[3]);
  p[4] = dppadd<0xB1>(p[4], p[5]);
  p[6] = dppadd<0xB1>(p[6], p[7]);
  p[0] = dppadd<0x4E>(p[0], p[2]);
  p[4] = dppadd<0x4E>(p[4], p[6]);
  p[0] = swz4add(p[0], p[4]);
  p[0] = dppadd<0x128>(p[0], p[0]);
  return p[0];
}

// ---------------------------------------------------------------------------
// K0: fill allf[:,128:224] with score|box|origin_score
// ---------------------------------------------------------------------------
__global__ void k_fill_misc(const float* __restrict__ score, const float* __restrict__ box,
                            const float* __restrict__ orig, float* __restrict__ allf) {
  int i = blockIdx.x * blockDim.x + threadIdx.x;
  if (i >= 40960 * 96) return;
  int row = i / 96, k = i - row * 96;
  float v;
  if (k == 0) v = score[row];
  else if (k < 5) v = box[row * 4 + (k - 1)];
  else v = orig[(size_t)row * 91 + (k - 5)];
  allf[(size_t)row * 224 + 128 + k] = v;
}

// ---------------------------------------------------------------------------
// K1: allf[:,0:128] = relu(feat @ appear_W^T + appear_b)
// ---------------------------------------------------------------------------
__global__ __launch_bounds__(256) void k_gemm_appear(
    const float* __restrict__ A, const float* __restrict__ W,
    const float* __restrict__ bias, float* __restrict__ allf) {
  __shared__ float As[32][68];
  __shared__ float Ws[32][132];
  const int tid = threadIdx.x;
  const int tx = tid & 15, ty = tid >> 4;
  const int r0 = blockIdx.x * 64;
  const int lr = tid >> 3;
  const int lk = (tid & 7) * 4;
  float acc[4][8];
#pragma unroll
  for (int i = 0; i < 4; ++i)
#pragma unroll
    for (int j = 0; j < 8; ++j) acc[i][j] = 0.f;

  for (int k0 = 0; k0 < 1024; k0 += 32) {
#pragma unroll
    for (int i = 0; i < 2; ++i) {
      int rr = lr + i * 32;
      float4 v = *(const float4*)(A + (size_t)(r0 + rr) * 1024 + k0 + lk);
      As[lk + 0][rr] = v.x; As[lk + 1][rr] = v.y; As[lk + 2][rr] = v.z; As[lk + 3][rr] = v.w;
    }
#pragma unroll
    for (int i = 0; i < 4; ++i) {
      int wr = lr + i * 32;
      float4 v = *(const float4*)(W + (size_t)wr * 1024 + k0 + lk);
      Ws[lk + 0][wr] = v.x; Ws[lk + 1][wr] = v.y; Ws[lk + 2][wr] = v.z; Ws[lk + 3][wr] = v.w;
    }
    __syncthreads();
#pragma unroll
    for (int kk = 0; kk < 32; ++kk) {
      float4 a = *(const float4*)&As[kk][ty * 4];
      float4 w0 = *(const float4*)&Ws[kk][tx * 8];
      float4 w1 = *(const float4*)&Ws[kk][tx * 8 + 4];
      float av[4] = {a.x, a.y, a.z, a.w};
      float wv[8] = {w0.x, w0.y, w0.z, w0.w, w1.x, w1.y, w1.z, w1.w};
#pragma unroll
      for (int i = 0; i < 4; ++i)
#pragma unroll
        for (int j = 0; j < 8; ++j) acc[i][j] = fmaf(av[i], wv[j], acc[i][j]);
    }
    __syncthreads();
  }
#pragma unroll
  for (int i = 0; i < 4; ++i) {
    int row = r0 + ty * 4 + i;
#pragma unroll
    for (int j = 0; j < 8; ++j) {
      int col = tx * 8 + j;
      float v = acc[i][j] + bias[col];
      allf[(size_t)row * 224 + col] = fmaxf(v, 0.f);
    }
  }
}

// ---------------------------------------------------------------------------
// K2: enc_feat = relu(allf @ featlin_W^T + b), stored packed f16x2
// ---------------------------------------------------------------------------
__global__ __launch_bounds__(256) void k_gemm_featlin(
    const float* __restrict__ A, const float* __restrict__ W,
    const float* __restrict__ bias, unsigned* __restrict__ encf2) {
  __shared__ float As[32][68];
  __shared__ float Ws[32][132];
  const int tid = threadIdx.x;
  const int tx = tid & 15, ty = tid >> 4;
  const int r0 = blockIdx.x * 64;
  const int lr = tid >> 3;
  const int lk = (tid & 7) * 4;
  float acc[4][8];
#pragma unroll
  for (int i = 0; i < 4; ++i)
#pragma unroll
    for (int j = 0; j < 8; ++j) acc[i][j] = 0.f;

  for (int k0 = 0; k0 < 224; k0 += 32) {
#pragma unroll
    for (int i = 0; i < 2; ++i) {
      int rr = lr + i * 32;
      float4 v = *(const float4*)(A + (size_t)(r0 + rr) * 224 + k0 + lk);
      As[lk + 0][rr] = v.x; As[lk + 1][rr] = v.y; As[lk + 2][rr] = v.z; As[lk + 3][rr] = v.w;
    }
#pragma unroll
    for (int i = 0; i < 4; ++i) {
      int wr = lr + i * 32;
      float4 v = *(const float4*)(W + (size_t)wr * 224 + k0 + lk);
      Ws[lk + 0][wr] = v.x; Ws[lk + 1][wr] = v.y; Ws[lk + 2][wr] = v.z; Ws[lk + 3][wr] = v.w;
    }
    __syncthreads();
#pragma unroll
    for (int kk = 0; kk < 32; ++kk) {
      float4 a = *(const float4*)&As[kk][ty * 4];
      float4 w0 = *(const float4*)&Ws[kk][tx * 8];
      float4 w1 = *(const float4*)&Ws[kk][tx * 8 + 4];
      float av[4] = {a.x, a.y, a.z, a.w};
      float wv[8] = {w0.x, w0.y, w0.z, w0.w, w1.x, w1.y, w1.z, w1.w};
#pragma unroll
      for (int i = 0; i < 4; ++i)
#pragma unroll
        for (int j = 0; j < 8; ++j) acc[i][j] = fmaf(av[i], wv[j], acc[i][j]);
    }
    __syncthreads();
  }
#pragma unroll
  for (int i = 0; i < 4; ++i) {
    int row = r0 + ty * 4 + i;
    unsigned* orow = encf2 + (size_t)row * 64;
#pragma unroll
    for (int p = 0; p < 4; ++p) {
      int col = tx * 8 + 2 * p;
      float a = fmaxf(acc[i][2 * p] + bias[col], 0.f);
      float b = fmaxf(acc[i][2 * p + 1] + bias[col + 1], 0.f);
      orow[tx * 4 + p] = h2u(pk2(a, b));
    }
  }
}

// ---------------------------------------------------------------------------
// K3: decoder input projections: gi[c][v][r] = dec_Wih[c][r]@dec_emb[v] + bih
// ---------------------------------------------------------------------------
__global__ __launch_bounds__(256) void k_dec_gi(
    const float* __restrict__ Wih, const float* __restrict__ bih,
    const float* __restrict__ emb, float* __restrict__ gi) {
  __shared__ float e[4][32];
  const int c = blockIdx.x, tid = threadIdx.x;
  if (tid < 128) e[tid >> 5][tid & 31] = emb[tid];
  __syncthreads();
#pragma unroll
  for (int i = 0; i < 3; ++i) {
    int r = tid + i * 256;
    const float* w = Wih + ((size_t)c * 768 + r) * 32;
    float b = bih[(size_t)c * 768 + r];
    float a0 = b, a1 = b, a2 = b, a3 = b;
#pragma unroll
    for (int k = 0; k < 32; ++k) {
      float wv = w[k];
      a0 = fmaf(wv, e[0][k], a0);
      a1 = fmaf(wv, e[1][k], a1);
      a2 = fmaf(wv, e[2][k], a2);
      a3 = fmaf(wv, e[3][k], a3);
    }
    gi[((size_t)c * 4 + 0) * 768 + r] = a0;
    gi[((size_t)c * 4 + 1) * 768 + r] = a1;
    gi[((size_t)c * 4 + 2) * 768 + r] = a2;
    gi[((size_t)c * 4 + 3) * 768 + r] = a3;
  }
}

// ---------------------------------------------------------------------------
// K4: per-(class,dir) encoder GRU, 513 steps. 160 blocks x 512 threads.
// 8 waves; each wave: 32 combined r/z rows (Wih·x + Whh·h fused) + 32 single
// rows (i_n for w<4, h_n for w>=4). 16-lane group owns 16 rows x 8 cols.
// Prologue fenced per row-group so in-flight loads never stack on top of the
// built weight array (the v3/v4 spill cause).
// ---------------------------------------------------------------------------
__global__ __launch_bounds__(512)
__attribute__((amdgpu_waves_per_eu(2, 2))) void k_enc_gru(
    const unsigned* __restrict__ encf2,
    const float* __restrict__ WihF, const float* __restrict__ WhhF,
    const float* __restrict__ bihF, const float* __restrict__ bhhF,
    const float* __restrict__ WihB, const float* __restrict__ WhhB,
    const float* __restrict__ bihB, const float* __restrict__ bhhB,
    float* __restrict__ dec_h0) {
  const int blk = blockIdx.x;
  const int c = blk >> 1, dir = blk & 1;
  const int tid = threadIdx.x;
  const int w = tid >> 6, l = tid & 63, q = l >> 4, m = l & 15, mw = m & 7;

  const float* Wih = (dir ? WihB : WihF) + (size_t)c * 384 * 128;
  const float* Whh = (dir ? WhhB : WhhF) + (size_t)c * 384 * 128;
  const float* bih = (dir ? bihB : bihF) + (size_t)c * 384;
  const float* bhh = (dir ? bhhB : bhhF) + (size_t)c * 384;

  __shared__ __align__(16) unsigned x2s[2][64];
  __shared__ __align__(16) unsigned h2s[64];
  __shared__ float aBuf[512];

  h2v wci[8][4], wch[8][4], wsg[8][4];
#pragma unroll
  for (int k = 0; k < 8; ++k) {
    int vc = 32 * w + 8 * q + (k ^ mw);
    {
      const float4* pi = (const float4*)(Wih + (size_t)vc * 128 + 8 * m);
      float4 a = pi[0], b = pi[1];
      wci[k][0] = pk2(a.x, a.y); wci[k][1] = pk2(a.z, a.w);
      wci[k][2] = pk2(b.x, b.y); wci[k][3] = pk2(b.z, b.w);
      __builtin_amdgcn_sched_barrier(0);
    }
    {
      const float4* ph = (const float4*)(Whh + (size_t)vc * 128 + 8 * m);
      float4 e = ph[0], f = ph[1];
      wch[k][0] = pk2(e.x, e.y); wch[k][1] = pk2(e.z, e.w);
      wch[k][2] = pk2(f.x, f.y); wch[k][3] = pk2(f.z, f.w);
      __builtin_amdgcn_sched_barrier(0);
    }
    {
      int s = (w < 4) ? (32 * w + 8 * q + (k ^ mw)) : (32 * (w - 4) + 8 * q + (k ^ mw));
      const float* sb = (w < 4) ? (Wih + (size_t)(256 + s) * 128) : (Whh + (size_t)(256 + s) * 128);
      const float4* ps = (const float4*)(sb + 8 * m);
      float4 g = ps[0], hh = ps[1];
      wsg[k][0] = pk2(g.x, g.y); wsg[k][1] = pk2(g.z, g.w);
      wsg[k][2] = pk2(hh.x, hh.y); wsg[k][3] = pk2(hh.z, hh.w);
      __builtin_amdgcn_sched_barrier(0);
    }
  }
  float bown;
  int ownIdx;
  if (m < 8) {
    int vo = 32 * w + 8 * q + m;
    bown = bih[vo] + bhh[vo];
    ownIdx = vo;
  } else {
    int so = (w < 4) ? (32 * w + 8 * q + mw) : (32 * (w - 4) + 8 * q + mw);
    bown = (w < 4) ? bih[256 + so] : bhh[256 + so];
    ownIdx = (w < 4) ? (256 + so) : (384 + so);
  }

  if (tid < 64) h2s[tid] = 0u;
  if (tid >= 448) {
    int lane = tid - 448;
    x2s[0][lane] = (dir == 0) ? encf2[((size_t)c * 512 + 0) * 64 + lane] : 0x3C003C00u;
  }
  float hreg = 0.f;
  __syncthreads();

  for (int t = 0; t <= 512; ++t) {
    unsigned xpre = 0;
    if (tid >= 448 && t < 512) {  // issue next-x load early; hides under matvec
      int tn = t + 1, lane = tid - 448;
      int row = (dir == 0) ? ((tn < 512) ? tn : -1) : (512 - tn);
      xpre = (row < 0) ? 0x3C003C00u : encf2[((size_t)c * 512 + row) * 64 + lane];
    }
    uint4 xv = ((const uint4*)&x2s[t & 1][0])[m];
    uint4 hv = ((const uint4*)&h2s[0])[m];
    h2v x0 = u2h(xv.x), x1 = u2h(xv.y), x2 = u2h(xv.z), x3 = u2h(xv.w);
    h2v g0 = u2h(hv.x), g1 = u2h(hv.y), g2 = u2h(hv.z), g3 = u2h(hv.w);
    float pA, pB;
    {
      float p[8];
#pragma unroll
      for (int k = 0; k < 8; ++k) {
        float a = 0.f;
        a = fdot2f(wci[k][0], x0, a); a = fdot2f(wci[k][1], x1, a);
        a = fdot2f(wci[k][2], x2, a); a = fdot2f(wci[k][3], x3, a);
        a = fdot2f(wch[k][0], g0, a); a = fdot2f(wch[k][1], g1, a);
        a = fdot2f(wch[k][2], g2, a); a = fdot2f(wch[k][3], g3, a);
        p[k] = a;
      }
      pA = reduce8(p);
    }
    {
      h2v s0 = (w < 4) ? x0 : g0, s1 = (w < 4) ? x1 : g1;
      h2v s2 = (w < 4) ? x2 : g2, s3 = (w < 4) ? x3 : g3;
      float p[8];
#pragma unroll
      for (int k = 0; k < 8; ++k) {
        float a = 0.f;
        a = fdot2f(wsg[k][0], s0, a); a = fdot2f(wsg[k][1], s1, a);
        a = fdot2f(wsg[k][2], s2, a); a = fdot2f(wsg[k][3], s3, a);
        p[k] = a;
      }
      pB = reduce8(p);
    }
    aBuf[ownIdx] = ((m < 8) ? pA : pB) + bown;
    __syncthreads();
    if (tid < 128) {
      float r = sigf(aBuf[tid]);
      float z = sigf(aBuf[128 + tid]);
      float nn = tanhfast(aBuf[256 + tid] + r * aBuf[384 + tid]);
      float hn = (1.f - z) * nn + z * hreg;
      hreg = hn;
      float other = __shfl_xor(hn, 1, 64);
      if ((tid & 1) == 0) h2s[tid >> 1] = h2u(pk2(hn, other));
    } else if (tid >= 448 && t < 512) {
      x2s[(t + 1) & 1][tid - 448] = xpre;
    }
    __syncthreads();
  }
  if (tid < 128) dec_h0[(size_t)c * 256 + dir * 128 + tid] = hreg;
}

// ---------------------------------------------------------------------------
// K5: per-class decoder GRU + fused out-projection + log_softmax.
// 80 blocks x 768 threads (12 waves = 3 waves/SIMD); wave owns 64 rows;
// 16-lane group owns 16 rows x 16 cols; 128 weight h2v per lane.
// waves_per_eu(3,3) + fenced prologue -> weights stay resident.
// ---------------------------------------------------------------------------
__global__ __launch_bounds__(768)
__attribute__((amdgpu_waves_per_eu(3, 3))) void k_dec_gru(
    const float* __restrict__ Whh, const float* __restrict__ bhh,
    const float* __restrict__ gi, const float* __restrict__ h0,
    const int* __restrict__ labels,
    const float* __restrict__ outW, const float* __restrict__ outB,
    float* __restrict__ out) {
  const int c = blockIdx.x, tid = threadIdx.x;
  const int w = tid >> 6, l = tid & 63, q = l >> 4, m = l & 15, mw = m & 7;

  __shared__ __align__(16) unsigned h2s[128];
  __shared__ float aBuf[768];
  __shared__ float gisf[2304];
  __shared__ float owsh[1024];
  __shared__ int labs[513];
  __shared__ float red[4][4];

  h2v wpk[2][8][8];
#pragma unroll
  for (int kc = 0; kc < 2; ++kc)
#pragma unroll
    for (int k = 0; k < 8; ++k) {
      int row = 64 * w + 16 * q + 8 * kc + (k ^ mw);
      const float4* src = (const float4*)(Whh + ((size_t)c * 768 + row) * 256 + 16 * m);
      float4 v0 = src[0], v1 = src[1];
      wpk[kc][k][0] = pk2(v0.x, v0.y); wpk[kc][k][1] = pk2(v0.z, v0.w);
      wpk[kc][k][2] = pk2(v1.x, v1.y); wpk[kc][k][3] = pk2(v1.z, v1.w);
      __builtin_amdgcn_sched_barrier(0);
      float4 v2 = src[2], v3 = src[3];
      wpk[kc][k][4] = pk2(v2.x, v2.y); wpk[kc][k][5] = pk2(v2.z, v2.w);
      wpk[kc][k][6] = pk2(v3.x, v3.y); wpk[kc][k][7] = pk2(v3.z, v3.w);
      __builtin_amdgcn_sched_barrier(0);
    }
  float bown = bhh[(size_t)c * 768 + 64 * w + l];

  for (int i = tid; i < 2304; i += 768) gisf[i] = gi[(size_t)c * 4 * 768 + i];
  for (int i = tid; i < 1024; i += 768) owsh[i] = outW[i];
  if (tid < 512) labs[tid + 1] = labels[(size_t)c * 512 + tid];
  if (tid == 512) labs[0] = 2;  // SOS
  float b0 = outB[0], b1 = outB[1], b2 = outB[2], b3 = outB[3];
  float hreg = 0.f;
  if (tid < 256) {
    hreg = h0[(size_t)c * 256 + tid];
    float other = __shfl_xor(hreg, 1, 64);
    if ((tid & 1) == 0) h2s[tid >> 1] = h2u(pk2(hreg, other));
  }
  __syncthreads();

  for (int t = 0; t <= 512; ++t) {
    const uint4* hp = (const uint4*)(&h2s[0]);
    uint4 ha = hp[2 * m], hb = hp[2 * m + 1];
    h2v g0 = u2h(ha.x), g1 = u2h(ha.y), g2 = u2h(ha.z), g3 = u2h(ha.w);
    h2v g4 = u2h(hb.x), g5 = u2h(hb.y), g6 = u2h(hb.z), g7 = u2h(hb.w);
    float pc0, pc1;
    {
      float p[8];
#pragma unroll
      for (int k = 0; k < 8; ++k) {
        float a = 0.f;
        a = fdot2f(wpk[0][k][0], g0, a); a = fdot2f(wpk[0][k][1], g1, a);
        a = fdot2f(wpk[0][k][2], g2, a); a = fdot2f(wpk[0][k][3], g3, a);
        a = fdot2f(wpk[0][k][4], g4, a); a = fdot2f(wpk[0][k][5], g5, a);
        a = fdot2f(wpk[0][k][6], g6, a); a = fdot2f(wpk[0][k][7], g7, a);
        p[k] = a;
      }
      pc0 = reduce8(p);
    }
    {
      float p[8];
#pragma unroll
      for (int k = 0; k < 8; ++k) {
        float a = 0.f;
        a = fdot2f(wpk[1][k][0], g0, a); a = fdot2f(wpk[1][k][1], g1, a);
        a = fdot2f(wpk[1][k][2], g2, a); a = fdot2f(wpk[1][k][3], g3, a);
        a = fdot2f(wpk[1][k][4], g4, a); a = fdot2f(wpk[1][k][5], g5, a);
        a = fdot2f(wpk[1][k][6], g6, a); a = fdot2f(wpk[1][k][7], g7, a);
        p[k] = a;
      }
      pc1 = reduce8(p);
    }
    aBuf[64 * w + l] = ((m < 8) ? pc0 : pc1) + bown;
    __syncthreads();
    if (tid < 256) {
      int sel = labs[t];
      const float* gsel = &gisf[sel * 768];
      float r = sigf(gsel[tid] + aBuf[tid]);
      float z = sigf(gsel[256 + tid] + aBuf[256 + tid]);
      float nn = tanhfast(gsel[512 + tid] + r * aBuf[512 + tid]);
      float hn = (1.f - z) * nn + z * hreg;
      hreg = hn;
      float other = __shfl_xor(hn, 1, 64);
      if ((tid & 1) == 0) h2s[tid >> 1] = h2u(pk2(hn, other));
      float p0 = owsh[tid] * hn, p1 = owsh[256 + tid] * hn;
      float p2 = owsh[512 + tid] * hn, p3 = owsh[768 + tid] * hn;
#pragma unroll
      for (int off = 32; off > 0; off >>= 1) {
        p0 += __shfl_xor(p0, off, 64);
        p1 += __shfl_xor(p1, off, 64);
        p2 += __shfl_xor(p2, off, 64);
        p3 += __shfl_xor(p3, off, 64);
      }
      if ((tid & 63) == 0) {
        int ww = tid >> 6;
        red[ww][0] = p0; red[ww][1] = p1; red[ww][2] = p2; red[ww][3] = p3;
      }
    }
    __syncthreads();
    if (tid == 0) {
      float l0 = red[0][0] + red[1][0] + red[2][0] + red[3][0] + b0;
      float l1 = red[0][1] + red[1][1] + red[2][1] + red[3][1] + b1;
      float l2 = red[0][2] + red[1][2] + red[2][2] + red[3][2] + b2;
      float l3 = red[0][3] + red[1][3] + red[2][3] + red[3][3] + b3;
      float mm = fmaxf(fmaxf(l0, l1), fmaxf(l2, l3));
      float s = __expf(l0 - mm) + __expf(l1 - mm) + __expf(l2 - mm) + __expf(l3 - mm);
      float lse = mm + __logf(s);
      float* o = out + ((size_t)c * 513 + t) * 4;
      o[0] = l0 - lse; o[1] = l1 - lse; o[2] = l2 - lse; o[3] = l3 - lse;
    }
  }
}

// ---------------------------------------------------------------------------
// K6: labels (as float) and weights passthrough
// ---------------------------------------------------------------------------
__global__ void k_passthrough(const int* __restrict__ labels,
                              const float* __restrict__ weights,
                              float* __restrict__ out) {
  int i = blockIdx.x * blockDim.x + threadIdx.x;
  if (i < 40960) {
    out[164160 + i] = (float)labels[i];
    out[164160 + 40960 + i] = weights[i];
  }
}

// ---------------------------------------------------------------------------
extern "C" void kernel_launch(void* const* d_in, const int* in_sizes, int n_in,
                              void* d_out, int out_size, void* d_ws, size_t ws_size,
                              hipStream_t stream) {
  (void)in_sizes; (void)n_in; (void)out_size; (void)ws_size;
  const float* feat = (const float*)d_in[0];
  const float* score = (const float*)d_in[1];
  const float* box = (const float*)d_in[2];
  const float* orig = (const float*)d_in[3];
  const int* labels = (const int*)d_in[4];
  const float* weights = (const float*)d_in[5];
  const float* appear_W = (const float*)d_in[8];
  const float* appear_b = (const float*)d_in[9];
  const float* featlin_W = (const float*)d_in[10];
  const float* featlin_b = (const float*)d_in[11];
  const float* eWihF = (const float*)d_in[12];
  const float* eWhhF = (const float*)d_in[13];
  const float* ebihF = (const float*)d_in[14];
  const float* ebhhF = (const float*)d_in[15];
  const float* eWihB = (const float*)d_in[16];
  const float* eWhhB = (const float*)d_in[17];
  const float* ebihB = (const float*)d_in[18];
  const float* ebhhB = (const float*)d_in[19];
  const float* dec_emb = (const float*)d_in[20];
  const float* dWih = (const float*)d_in[21];
  const float* dWhh = (const float*)d_in[22];
  const float* dbih = (const float*)d_in[23];
  const float* dbhh = (const float*)d_in[24];
  const float* outW = (const float*)d_in[25];
  const float* outB = (const float*)d_in[26];
  float* out = (float*)d_out;

  char* ws = (char*)d_ws;
  float* allf = (float*)ws;                                     // 40960*224 f32
  unsigned* encf2 = (unsigned*)(ws + (size_t)40960 * 224 * 4);  // 40960*64 u32
  float* dec_h0 = (float*)(ws + (size_t)40960 * 224 * 4 + (size_t)40960 * 64 * 4);
  float* dec_gi = dec_h0 + 80 * 256;                            // 80*4*768 f32

  k_fill_misc<<<15360, 256, 0, stream>>>(score, box, orig, allf);
  k_gemm_appear<<<640, 256, 0, stream>>>(feat, appear_W, appear_b, allf);
  k_gemm_featlin<<<640, 256, 0, stream>>>(allf, featlin_W, featlin_b, encf2);
  k_dec_gi<<<80, 256, 0, stream>>>(dWih, dbih, dec_emb, dec_gi);
  k_enc_gru<<<160, 512, 0, stream>>>(encf2, eWihF, eWhhF, ebihF, ebhhF,
                                     eWihB, eWhhB, ebihB, ebhhB, dec_h0);
  k_dec_gru<<<80, 768, 0, stream>>>(dWhh, dbhh, dec_gi, dec_h0, labels, outW, outB, out);
  k_passthrough<<<160, 256, 0, stream>>>(labels, weights, out);
}